// Round 13
// baseline (158.571 us; speedup 1.0000x reference)
//
#include <hip/hip_runtime.h>

typedef unsigned short u16;
typedef __bf16 bf16;
typedef float f32x4 __attribute__((ext_vector_type(4)));
typedef bf16 bf16x8 __attribute__((ext_vector_type(8)));
typedef short s16x4 __attribute__((ext_vector_type(4)));
typedef u16 u16x4 __attribute__((ext_vector_type(4)));
typedef u16 u16x8 __attribute__((ext_vector_type(8)));

#define SEQ 2048
#define LOG2E 1.4426950408889634f

__device__ __forceinline__ u16 f2bf(float f) {
    return __builtin_bit_cast(u16, (bf16)f);
}
__device__ __forceinline__ float bf2f(u16 u) {
    unsigned int w = ((unsigned int)u) << 16;
    return __builtin_bit_cast(float, w);
}

// ---------------- cast f32 -> bf16 (vectorized) ----------------
__global__ __launch_bounds__(256) void cast_bf16_k(const float* __restrict__ in,
                                                   u16* __restrict__ out, int n4) {
    int i = blockIdx.x * 256 + threadIdx.x;
    int stride = gridDim.x * 256;
    for (; i < n4; i += stride) {
        float4 v = reinterpret_cast<const float4*>(in)[i];
        u16x4 o;
        o[0] = f2bf(v.x); o[1] = f2bf(v.y); o[2] = f2bf(v.z); o[3] = f2bf(v.w);
        reinterpret_cast<u16x4*>(out)[i] = o;
    }
}

// ---------------- transpose + cast: src f32 [R][C] -> dst bf16 [C][R] ----------------
__global__ __launch_bounds__(256) void transpose_cast_k(const float* __restrict__ src,
                                                        u16* __restrict__ dst, int R, int C) {
    __shared__ float t[64][65];
    int c0 = blockIdx.x * 64, r0 = blockIdx.y * 64;
    int tx = threadIdx.x & 63, ty = threadIdx.x >> 6;
#pragma unroll
    for (int i = 0; i < 16; ++i) {
        int r = ty + i * 4;
        t[r][tx] = src[(size_t)(r0 + r) * C + c0 + tx];
    }
    __syncthreads();
#pragma unroll
    for (int i = 0; i < 16; ++i) {
        int c = ty + i * 4;
        dst[(size_t)(c0 + c) * R + r0 + tx] = f2bf(t[tx][c]);
    }
}

// ---------------- GEMM partial: Cp[z][M,N](bf16) = A[M,kz] @ Bt[N,kz]^T ----------------
// 128x128 tile, BK=32, split-K = gridDim.z (R13: 4 — at 2048-class shapes 128^2 tiles
// give only 2-3 blocks/CU total vs the 3-resident register cap; split-K=4 creates a
// refill stream: 1536/1024 blocks), double-buffered LDS with prefetch, XOR-swizzled
// LDS slots (pre-swizzled gload_lds source + swizzled ds_read; rule #21).
__global__ __launch_bounds__(256) void gemm_bt_dbuf_k(const u16* __restrict__ A,
                                                      const u16* __restrict__ Bt,
                                                      u16* __restrict__ Cp,
                                                      int M, int N, int K) {
    __shared__ __align__(16) u16 As[2][128 * 32];
    __shared__ __align__(16) u16 Bs[2][128 * 32];
    int tid = threadIdx.x;
    int wave = tid >> 6, lane = tid & 63;
    int bm = blockIdx.y * 128, bn = blockIdx.x * 128;
    int z = blockIdx.z;
    int kslice = K / gridDim.z;             // multiple of 32 for all our shapes
    int kt0 = z * kslice, ktend = kt0 + kslice;
    int wm = (wave >> 1) * 64, wn = (wave & 1) * 64;
    int g = lane >> 4, cidx = lane & 15;
    f32x4 acc[4][4] = {};

    // staging: LDS slot (srow, lane&3) holds global k-chunk (lane&3) ^ ((srow>>1)&3)
    int srow = lane >> 2;
    int skol = ((lane & 3) ^ ((srow >> 1) & 3)) * 8;
    // read: logical chunk g of row r lives at slot g ^ ((r_in16>>1)&3); r_in16 = cidx
    int sl8 = (g ^ ((cidx >> 1) & 3)) * 8;

#define STAGE(buf, kt)                                                                \
    {                                                                                 \
        _Pragma("unroll")                                                             \
        for (int j = 0; j < 2; ++j) {                                                 \
            const u16* gpa = A + (size_t)(bm + (wave * 2 + j) * 16 + srow) * K + (kt) + skol; \
            __builtin_amdgcn_global_load_lds(                                         \
                (__attribute__((address_space(1))) void*)gpa,                         \
                (__attribute__((address_space(3))) void*)&As[buf][(wave * 2 + j) * 512], \
                16, 0, 0);                                                            \
        }                                                                             \
        _Pragma("unroll")                                                             \
        for (int j = 0; j < 2; ++j) {                                                 \
            const u16* gpb = Bt + (size_t)(bn + (wave * 2 + j) * 16 + srow) * K + (kt) + skol; \
            __builtin_amdgcn_global_load_lds(                                         \
                (__attribute__((address_space(1))) void*)gpb,                         \
                (__attribute__((address_space(3))) void*)&Bs[buf][(wave * 2 + j) * 512], \
                16, 0, 0);                                                            \
        }                                                                             \
    }

    STAGE(0, kt0);
    asm volatile("s_waitcnt vmcnt(0)" ::: "memory");
    __syncthreads();

    int cur = 0;
#pragma unroll 1
    for (int kt = kt0; kt < ktend; kt += 32) {
        if (kt + 32 < ktend) STAGE(cur ^ 1, kt + 32);  // prefetch in flight across compute

        bf16x8 af[4], bfr[4];
#pragma unroll
        for (int mi = 0; mi < 4; ++mi)
            af[mi] = *reinterpret_cast<const bf16x8*>(&As[cur][(wm + mi * 16 + cidx) * 32 + sl8]);
#pragma unroll
        for (int ni = 0; ni < 4; ++ni)
            bfr[ni] = *reinterpret_cast<const bf16x8*>(&Bs[cur][(wn + ni * 16 + cidx) * 32 + sl8]);
#pragma unroll
        for (int mi = 0; mi < 4; ++mi)
#pragma unroll
            for (int ni = 0; ni < 4; ++ni)
                acc[mi][ni] = __builtin_amdgcn_mfma_f32_16x16x32_bf16(af[mi], bfr[ni], acc[mi][ni], 0, 0, 0);

        asm volatile("s_waitcnt vmcnt(0)" ::: "memory");
        __syncthreads();
        cur ^= 1;
    }
#undef STAGE

    u16* cbase = Cp + (size_t)z * M * N;
#pragma unroll
    for (int mi = 0; mi < 4; ++mi) {
#pragma unroll
        for (int r = 0; r < 4; ++r) {
            int row = bm + wm + mi * 16 + g * 4 + r;
            u16* cp = cbase + (size_t)row * N + bn + wn + cidx;
#pragma unroll
            for (int ni = 0; ni < 4; ++ni)
                cp[ni * 16] = f2bf(acc[mi][ni][r]);
        }
    }
}

// ---------------- sum four bf16 partials -> f32 ----------------
__global__ __launch_bounds__(256) void sum4_f32_k(const u16* __restrict__ p,
                                                  float* __restrict__ out, int n8) {
    int i = blockIdx.x * 256 + threadIdx.x;
    if (i >= n8) return;
    const size_t MN8 = (size_t)2048 * 2048 / 8;
    u16x8 v0 = reinterpret_cast<const u16x8*>(p)[i];
    u16x8 v1 = reinterpret_cast<const u16x8*>(p)[i + MN8];
    u16x8 v2 = reinterpret_cast<const u16x8*>(p)[i + 2 * MN8];
    u16x8 v3 = reinterpret_cast<const u16x8*>(p)[i + 3 * MN8];
    f32x4 lo, hi;
#pragma unroll
    for (int j = 0; j < 4; ++j) {
        lo[j] = (bf2f(v0[j]) + bf2f(v1[j])) + (bf2f(v2[j]) + bf2f(v3[j]));
        hi[j] = (bf2f(v0[4 + j]) + bf2f(v1[4 + j])) + (bf2f(v2[4 + j]) + bf2f(v3[4 + j]));
    }
    reinterpret_cast<f32x4*>(out)[i * 2] = lo;
    reinterpret_cast<f32x4*>(out)[i * 2 + 1] = hi;
}

// ---------------- RMSNorm + RoPE for Q and K heads (sums 4 split-K partials) ----------------
// Q: pre-scaled by 0.125*log2(e) (exp2-base softmax), row-major [s][32*64]
// K: MFMA A-fragment order with PERMUTED key placement inside each 32-key group:
//   k32 -> phys (sub = bit2, row = (k32>>3)*4 + (k32&3)); this makes two QK 16-subs
//   concatenate into a K=32 PV B-fragment (lane g holds keys g*8..g*8+7).
__global__ __launch_bounds__(256) void norm_rope_k(const u16* __restrict__ pp,
                                                   const float* __restrict__ cosb,
                                                   const float* __restrict__ sinb,
                                                   const float* __restrict__ qw,
                                                   const float* __restrict__ kw,
                                                   u16* __restrict__ qn,
                                                   u16* __restrict__ kfrag) {
    int idx = blockIdx.x * 4 + (threadIdx.x >> 6);
    int lane = threadIdx.x & 63;
    int s = idx / 40, hh = idx - s * 40;
    size_t off = (hh < 32) ? ((size_t)s * 3072 + hh * 64 + lane)
                           : ((size_t)s * 3072 + 2048 + (hh - 32) * 64 + lane);
    const size_t MN = (size_t)2048 * 3072;
    float val = (bf2f(pp[off]) + bf2f(pp[off + MN])) + (bf2f(pp[off + 2 * MN]) + bf2f(pp[off + 3 * MN]));
    float ss = val * val;
#pragma unroll
    for (int mm = 32; mm; mm >>= 1) ss += __shfl_xor(ss, mm);
    float w = (hh < 32) ? qw[lane] : kw[lane];
    float xn = val * rsqrtf(ss * (1.f / 64.f) + 1e-6f) * w;
    float part = __shfl_xor(xn, 32);
    float rot = (lane < 32) ? -part : part;
    float o = xn * cosb[s * 64 + lane] + rot * sinb[s * 64 + lane];
    if (hh < 32) {
        qn[(size_t)s * 2048 + hh * 64 + lane] = f2bf(o * (0.125f * LOG2E));
    } else {
        int h8 = hh - 32;
        int k32 = s & 31;
        int p32 = ((k32 >> 2) & 1) * 16 + ((k32 >> 3) << 2) + (k32 & 3);
        int p = (s & ~31) + p32;
        kfrag[(((size_t)h8 * 128 + (p >> 4)) << 10) + (lane >> 3) * 128 + (p & 15) * 8 + (lane & 7)] = f2bf(o);
    }
}

// ---------------- V in K=32 PV A-fragment order (sums 4 split-K partials) ----------------
// vfrag[kvh][kb32][dt][lane(g*16+cc)][i] = V[kb32*32 + g*8 + i][dt*16 + cc]
__global__ __launch_bounds__(256) void v_frag_k(const u16* __restrict__ pp,
                                                u16* __restrict__ vfrag) {
    __shared__ float t[64][65];
    int s0 = blockIdx.x * 64;
    int h = blockIdx.y;
    int tx = threadIdx.x & 63, ty = threadIdx.x >> 6;
    const size_t MN = (size_t)2048 * 3072;
#pragma unroll
    for (int i = 0; i < 16; ++i) {
        int r = ty + i * 4;
        size_t off = (size_t)(s0 + r) * 3072 + 2560 + h * 64 + tx;
        t[r][tx] = (bf2f(pp[off]) + bf2f(pp[off + MN])) + (bf2f(pp[off + 2 * MN]) + bf2f(pp[off + 3 * MN]));
    }
    __syncthreads();
    int dt = threadIdx.x >> 6, g = (threadIdx.x >> 4) & 3, cc = threadIdx.x & 15;
#pragma unroll
    for (int kb = 0; kb < 2; ++kb) {
        u16x8 o;
#pragma unroll
        for (int i = 0; i < 8; ++i) o[i] = f2bf(t[kb * 32 + g * 8 + i][dt * 16 + cc]);
        *reinterpret_cast<u16x8*>(
            &vfrag[((size_t)h * 64 + (s0 >> 5) + kb) * 2048 + dt * 512 + (size_t)(threadIdx.x & 63) * 8]) = o;
    }
}

// ---------------- Flash attention: 32 q-rows/wave, shared K/V, sequential streams ----------------
// 1-wave blocks; wave owns chunks c=2t (A) and c=2t+1 (B) over key-window w (512 keys,
// <=8 iterations -> no long critical path). Per 64-key iteration: load K+V ONCE, then
// A's QK->softmax->PV followed by B's (SEQUENTIAL register lifetime for st/pb -- R9's
// interleaved version spilled ~190 regs; this peaks ~145 under the (64,3) cap ~170).
// Halves memory-path bytes per FLOP vs 16-row waves (the R7-R11 invariant bottleneck).
// item -> (t,w): R9's 160-item mapping; partial o (bf16) + l slots, merged by merge_k.
// NOTE: VGPR caps: (256,8)->32 regs spilled 1.3GB (R4); interleaved dual-stream ~190
// regs spilled (R9). Tripwire: FETCH/WRITE >> 30MB means spill.
__global__ __launch_bounds__(64, 3) void attn_k(const u16* __restrict__ qn,
                                                const u16* __restrict__ kfrag,
                                                const u16* __restrict__ vfrag,
                                                u16* __restrict__ obuf,
                                                float* __restrict__ lbuf) {
    int h = blockIdx.x;
    int kvh = h >> 2;
    int lane = threadIdx.x;
    int item = 159 - blockIdx.y;   // reversed: 4-window pairs (most iters) first
    int t, w;
    if (item < 16)      { t = item;                    w = 0; }
    else if (item < 48) { t = 16 + ((item - 16) >> 1); w = (item - 16) & 1; }
    else if (item < 96) { int r = item - 48; int q = r / 3; t = 32 + q; w = r - 3 * q; }
    else                { t = 48 + ((item - 96) >> 2); w = (item - 96) & 3; }

    int qA0 = t * 32;          // chunk 2t   rows [qA0, qA0+16)
    int qB0 = qA0 + 16;        // chunk 2t+1 rows [qB0, qB0+16)
    int kv0 = w * 512;
    int nkA = qA0 + 16, nkB = qB0 + 16;
    int kvend = (kv0 + 512 < nkB) ? (kv0 + 512) : nkB;

    int g = lane >> 4, cc = lane & 15;
    int qrowA = qA0 + cc, qrowB = qB0 + cc;

    const size_t qoffA = (size_t)qrowA * 2048 + h * 64;
    const size_t qoffB = (size_t)qrowB * 2048 + h * 64;
    bf16x8 qa0 = *reinterpret_cast<const bf16x8*>(&qn[qoffA + g * 8]);
    bf16x8 qa1 = *reinterpret_cast<const bf16x8*>(&qn[qoffA + 32 + g * 8]);
    bf16x8 qb0 = *reinterpret_cast<const bf16x8*>(&qn[qoffB + g * 8]);
    bf16x8 qb1 = *reinterpret_cast<const bf16x8*>(&qn[qoffB + 32 + g * 8]);

    float lA = 0.f, lB = 0.f;
    f32x4 oA[4] = {}, oB[4] = {};

    const u16* kbase = kfrag + (((size_t)kvh * 128) << 10) + lane * 8;
    const u16* vbase = vfrag + (size_t)kvh * 64 * 2048 + lane * 8;

#pragma unroll 1
    for (; kv0 < kvend; kv0 += 64) {
        // K + V loads for this block (one set, shared by both streams)
        bf16x8 kf0[4], kf1[4], vv[2][4];
#pragma unroll
        for (int sub = 0; sub < 4; ++sub) {
            const u16* kp = kbase + (size_t)((kv0 >> 4) + sub) * 1024;
            kf0[sub] = *reinterpret_cast<const bf16x8*>(kp);
            kf1[sub] = *reinterpret_cast<const bf16x8*>(kp + 512);
        }
#pragma unroll
        for (int sp = 0; sp < 2; ++sp)
#pragma unroll
            for (int dt = 0; dt < 4; ++dt)
                vv[sp][dt] = *reinterpret_cast<const bf16x8*>(
                    vbase + (size_t)((kv0 >> 5) + sp) * 2048 + dt * 512);

        bool doA = kv0 < nkA;   // wave-uniform: A's range is 32 keys shorter

        // ---- stream A (st/pb live only in this span) ----
        if (doA) {
            f32x4 st[4];
            __builtin_amdgcn_s_setprio(1);
#pragma unroll
            for (int sub = 0; sub < 4; ++sub) {
                st[sub] = __builtin_amdgcn_mfma_f32_16x16x32_bf16(kf0[sub], qa0, (f32x4){0.f, 0.f, 0.f, 0.f}, 0, 0, 0);
                st[sub] = __builtin_amdgcn_mfma_f32_16x16x32_bf16(kf1[sub], qa1, st[sub], 0, 0, 0);
            }
            __builtin_amdgcn_s_setprio(0);
            if (kv0 + 64 > qA0) {
#pragma unroll
                for (int sub = 0; sub < 4; ++sub)
#pragma unroll
                    for (int r = 0; r < 4; ++r) {
                        int key = kv0 + (sub >> 1) * 32 + g * 8 + (sub & 1) * 4 + r;
                        if (key > qrowA) st[sub][r] = -1e30f;
                    }
            }
            u16x8 pb[2];
            float rs = 0.f;
#pragma unroll
            for (int sub = 0; sub < 4; ++sub)
#pragma unroll
                for (int r = 0; r < 4; ++r) {
                    float e = __builtin_amdgcn_exp2f(st[sub][r]);
                    rs += e;
                    pb[sub >> 1][(sub & 1) * 4 + r] = f2bf(e);
                }
            lA += rs;
            __builtin_amdgcn_s_setprio(1);
#pragma unroll
            for (int sp = 0; sp < 2; ++sp) {
                bf16x8 pbb = __builtin_bit_cast(bf16x8, pb[sp]);
#pragma unroll
                for (int dt = 0; dt < 4; ++dt)
                    oA[dt] = __builtin_amdgcn_mfma_f32_16x16x32_bf16(vv[sp][dt], pbb, oA[dt], 0, 0, 0);
            }
            __builtin_amdgcn_s_setprio(0);
        }

        // ---- stream B ----
        {
            f32x4 st[4];
            __builtin_amdgcn_s_setprio(1);
#pragma unroll
            for (int sub = 0; sub < 4; ++sub) {
                st[sub] = __builtin_amdgcn_mfma_f32_16x16x32_bf16(kf0[sub], qb0, (f32x4){0.f, 0.f, 0.f, 0.f}, 0, 0, 0);
                st[sub] = __builtin_amdgcn_mfma_f32_16x16x32_bf16(kf1[sub], qb1, st[sub], 0, 0, 0);
            }
            __builtin_amdgcn_s_setprio(0);
            if (kv0 + 64 > qB0) {
#pragma unroll
                for (int sub = 0; sub < 4; ++sub)
#pragma unroll
                    for (int r = 0; r < 4; ++r) {
                        int key = kv0 + (sub >> 1) * 32 + g * 8 + (sub & 1) * 4 + r;
                        if (key > qrowB) st[sub][r] = -1e30f;
                    }
            }
            u16x8 pb[2];
            float rs = 0.f;
#pragma unroll
            for (int sub = 0; sub < 4; ++sub)
#pragma unroll
                for (int r = 0; r < 4; ++r) {
                    float e = __builtin_amdgcn_exp2f(st[sub][r]);
                    rs += e;
                    pb[sub >> 1][(sub & 1) * 4 + r] = f2bf(e);
                }
            lB += rs;
            __builtin_amdgcn_s_setprio(1);
#pragma unroll
            for (int sp = 0; sp < 2; ++sp) {
                bf16x8 pbb = __builtin_bit_cast(bf16x8, pb[sp]);
#pragma unroll
                for (int dt = 0; dt < 4; ++dt)
                    oB[dt] = __builtin_amdgcn_mfma_f32_16x16x32_bf16(vv[sp][dt], pbb, oB[dt], 0, 0, 0);
            }
            __builtin_amdgcn_s_setprio(0);
        }
    }

    // private-slot partial writes (plain stores, no atomics); slot = (h*160+item)*2+half
    lA += __shfl_xor(lA, 16);
    lA += __shfl_xor(lA, 32);
    lB += __shfl_xor(lB, 16);
    lB += __shfl_xor(lB, 32);
    size_t slotA = ((size_t)h * 160 + item) * 2;
    if (lane < 16) {
        lbuf[slotA * 16 + cc] = lA;
        lbuf[(slotA + 1) * 16 + cc] = lB;
    }
    u16* spA = obuf + slotA * 1024;
    u16* spB = obuf + (slotA + 1) * 1024;
#pragma unroll
    for (int dt = 0; dt < 4; ++dt) {
        u16x4 ovA, ovB;
#pragma unroll
        for (int r = 0; r < 4; ++r) {
            ovA[r] = f2bf(oA[dt][r]);
            ovB[r] = f2bf(oB[dt][r]);
        }
        *reinterpret_cast<u16x4*>(&spA[cc * 64 + dt * 16 + g * 4]) = ovA;
        *reinterpret_cast<u16x4*>(&spB[cc * 64 + dt * 16 + g * 4]) = ovB;
    }
}

// ---------------- merge: attn_bf16 = sum(o_w) / (sum(l_w) + 2^(sink*log2e)) ----------------
__global__ __launch_bounds__(256) void merge_k(const u16* __restrict__ obuf,
                                               const float* __restrict__ lbuf,
                                               const float* __restrict__ sink,
                                               u16* __restrict__ attnb) {
    int row = blockIdx.x;
    int c = row >> 4, cc = row & 15;
    int t2 = c >> 1, half = c & 1;
    int nw = (t2 >> 4) + 1;  // windows for this 32-row pair
    int jb = (t2 < 16) ? t2
           : (t2 < 32) ? 16 + ((t2 - 16) << 1)
           : (t2 < 48) ? 48 + 3 * (t2 - 32)
                       : 96 + ((t2 - 48) << 2);
    int t = threadIdx.x;
    int h = t >> 3, col0 = (t & 7) * 8;

    float acc[8] = {};
    float lsum = __builtin_amdgcn_exp2f(sink[h] * LOG2E);
#pragma unroll 1
    for (int w = 0; w < nw; ++w) {
        size_t slot = ((size_t)h * 160 + jb + w) * 2 + half;
        lsum += lbuf[slot * 16 + cc];
        u16x8 v = *reinterpret_cast<const u16x8*>(&obuf[slot * 1024 + cc * 64 + col0]);
#pragma unroll
        for (int i = 0; i < 8; ++i) acc[i] += bf2f(v[i]);
    }
    float inv = 1.f / lsum;
    u16x8 ob;
#pragma unroll
    for (int i = 0; i < 8; ++i) ob[i] = f2bf(acc[i] * inv);
    *reinterpret_cast<u16x8*>(&attnb[(size_t)row * 2048 + h * 64 + col0]) = ob;
}

extern "C" void kernel_launch(void* const* d_in, const int* in_sizes, int n_in,
                              void* d_out, int out_size, void* d_ws, size_t ws_size,
                              hipStream_t stream) {
    const float* x    = (const float*)d_in[0];
    const float* cosb = (const float*)d_in[2];
    const float* sinb = (const float*)d_in[3];
    const float* wq   = (const float*)d_in[4];
    const float* wk   = (const float*)d_in[5];
    const float* wv   = (const float*)d_in[6];
    const float* wo   = (const float*)d_in[7];
    const float* qw   = (const float*)d_in[8];
    const float* kw   = (const float*)d_in[9];
    const float* sink = (const float*)d_in[10];
    float* out = (float*)d_out;

    char* ws = (char*)d_ws;
    size_t off = 0;
    auto alloc = [&](size_t bytes) {
        char* p = ws + off;
        off += (bytes + 255) & ~(size_t)255;
        return p;
    };
    u16*   xb    = (u16*)alloc((size_t)2048 * 2048 * 2);           // x bf16
    u16*   wqkvt = (u16*)alloc((size_t)3072 * 2048 * 2);           // [wq^T; wk^T; wv^T]
    u16*   wot   = (u16*)alloc((size_t)2048 * 2048 * 2);           // wo^T
    u16*   pq    = (u16*)alloc((size_t)4 * 2048 * 3072 * 2);       // GEMM1 partials z=0..3 (bf16, 50.3 MB)
    u16*   qnb   = (u16*)alloc((size_t)2048 * 2048 * 2);
    u16*   kfrag = (u16*)alloc((size_t)8 * 128 * 1024 * 2);
    u16*   vfrag = (u16*)alloc((size_t)8 * 64 * 2048 * 2);
    float* lbuf  = (float*)alloc((size_t)32 * 320 * 16 * 4);
    u16*   attnb = xb;        // xb dead after GEMM1
    u16*   obuf  = pq;        // pq (50.3 MB) dead after norm_rope/v_frag; obuf needs 21 MB
    u16*   o2p   = pq;        // obuf dead after merge_k; GEMM2 partials need 4 x 8.4 = 33.6 MB

    cast_bf16_k<<<2048, 256, 0, stream>>>(x, xb, 2048 * 2048 / 4);
    transpose_cast_k<<<dim3(32, 32), 256, 0, stream>>>(wq, wqkvt, 2048, 2048);
    transpose_cast_k<<<dim3(8, 32), 256, 0, stream>>>(wk, wqkvt + (size_t)2048 * 2048, 2048, 512);
    transpose_cast_k<<<dim3(8, 32), 256, 0, stream>>>(wv, wqkvt + (size_t)2560 * 2048, 2048, 512);
    transpose_cast_k<<<dim3(32, 32), 256, 0, stream>>>(wo, wot, 2048, 2048);

    gemm_bt_dbuf_k<<<dim3(24, 16, 4), 256, 0, stream>>>(xb, wqkvt, pq, 2048, 3072, 2048);
    norm_rope_k<<<20480, 256, 0, stream>>>(pq, cosb, sinb, qw, kw, qnb, kfrag);
    v_frag_k<<<dim3(32, 8), 256, 0, stream>>>(pq, vfrag);

    attn_k<<<dim3(32, 160), 64, 0, stream>>>(qnb, kfrag, vfrag, obuf, lbuf);
    merge_k<<<2048, 256, 0, stream>>>(obuf, lbuf, sink, attnb);

    gemm_bt_dbuf_k<<<dim3(16, 16, 4), 256, 0, stream>>>(attnb, wot, o2p, 2048, 2048, 2048);
    sum4_f32_k<<<2048, 256, 0, stream>>>(o2p, out, 2048 * 2048 / 8);
}

// Round 14
// 147.691 us; speedup vs baseline: 1.0737x; 1.0737x over previous
//
#include <hip/hip_runtime.h>

typedef unsigned short u16;
typedef __bf16 bf16;
typedef float f32x4 __attribute__((ext_vector_type(4)));
typedef bf16 bf16x8 __attribute__((ext_vector_type(8)));
typedef short s16x4 __attribute__((ext_vector_type(4)));
typedef u16 u16x4 __attribute__((ext_vector_type(4)));
typedef u16 u16x8 __attribute__((ext_vector_type(8)));

#define SEQ 2048
#define LOG2E 1.4426950408889634f

__device__ __forceinline__ u16 f2bf(float f) {
    return __builtin_bit_cast(u16, (bf16)f);
}
__device__ __forceinline__ float bf2f(u16 u) {
    unsigned int w = ((unsigned int)u) << 16;
    return __builtin_bit_cast(float, w);
}

// ---------------- cast f32 -> bf16 (vectorized) ----------------
__global__ __launch_bounds__(256) void cast_bf16_k(const float* __restrict__ in,
                                                   u16* __restrict__ out, int n4) {
    int i = blockIdx.x * 256 + threadIdx.x;
    int stride = gridDim.x * 256;
    for (; i < n4; i += stride) {
        float4 v = reinterpret_cast<const float4*>(in)[i];
        u16x4 o;
        o[0] = f2bf(v.x); o[1] = f2bf(v.y); o[2] = f2bf(v.z); o[3] = f2bf(v.w);
        reinterpret_cast<u16x4*>(out)[i] = o;
    }
}

// ---------------- transpose + cast: src f32 [R][C] -> dst bf16 [C][R] ----------------
__global__ __launch_bounds__(256) void transpose_cast_k(const float* __restrict__ src,
                                                        u16* __restrict__ dst, int R, int C) {
    __shared__ float t[64][65];
    int c0 = blockIdx.x * 64, r0 = blockIdx.y * 64;
    int tx = threadIdx.x & 63, ty = threadIdx.x >> 6;
#pragma unroll
    for (int i = 0; i < 16; ++i) {
        int r = ty + i * 4;
        t[r][tx] = src[(size_t)(r0 + r) * C + c0 + tx];
    }
    __syncthreads();
#pragma unroll
    for (int i = 0; i < 16; ++i) {
        int c = ty + i * 4;
        dst[(size_t)(c0 + c) * R + r0 + tx] = f2bf(t[tx][c]);
    }
}

// ---------------- GEMM partial: Cp[z][M,N](bf16) = A[M,kz] @ Bt[N,kz]^T ----------------
// 128x128 tile, BK=32, split-K=2, TRIPLE-buffered LDS + counted vmcnt (T3/T4):
// loop-top waits vmcnt(8) (only the OLDEST stage's 4 per-wave loads; 8 newer stay in
// flight ACROSS the barrier — never vmcnt(0) in the loop). Tail iterations stage a
// dummy (kt0) so outstanding count is ALWAYS 12 and vmcnt(8) is exact.
// R12/R13 post-mortem: per-iter vmcnt(0) drain made both GEMMs latency-bound at
// ~3000 cyc/iter regardless of blocks/CU (39.5 us at 2 AND 3 blocks/CU).
// XOR-swizzled LDS slots (pre-swizzled gload_lds source + swizzled ds_read; rule #21).
__global__ __launch_bounds__(256) void gemm_bt_dbuf_k(const u16* __restrict__ A,
                                                      const u16* __restrict__ Bt,
                                                      u16* __restrict__ Cp,
                                                      int M, int N, int K) {
    __shared__ __align__(16) u16 As[3][128 * 32];
    __shared__ __align__(16) u16 Bs[3][128 * 32];
    int tid = threadIdx.x;
    int wave = tid >> 6, lane = tid & 63;
    int bm = blockIdx.y * 128, bn = blockIdx.x * 128;
    int z = blockIdx.z;
    int kslice = K / gridDim.z;
    int kt0 = z * kslice, ktend = kt0 + kslice;
    int wm = (wave >> 1) * 64, wn = (wave & 1) * 64;
    int g = lane >> 4, cidx = lane & 15;
    f32x4 acc[4][4] = {};

    // staging: LDS slot (srow, lane&3) holds global k-chunk (lane&3) ^ ((srow>>1)&3)
    int srow = lane >> 2;
    int skol = ((lane & 3) ^ ((srow >> 1) & 3)) * 8;
    // read: logical chunk g of row r lives at slot g ^ ((r_in16>>1)&3); r_in16 = cidx
    int sl8 = (g ^ ((cidx >> 1) & 3)) * 8;

#define STAGE(buf, kt)                                                                \
    {                                                                                 \
        _Pragma("unroll")                                                             \
        for (int j = 0; j < 2; ++j) {                                                 \
            const u16* gpa = A + (size_t)(bm + (wave * 2 + j) * 16 + srow) * K + (kt) + skol; \
            __builtin_amdgcn_global_load_lds(                                         \
                (__attribute__((address_space(1))) void*)gpa,                         \
                (__attribute__((address_space(3))) void*)&As[buf][(wave * 2 + j) * 512], \
                16, 0, 0);                                                            \
        }                                                                             \
        _Pragma("unroll")                                                             \
        for (int j = 0; j < 2; ++j) {                                                 \
            const u16* gpb = Bt + (size_t)(bn + (wave * 2 + j) * 16 + srow) * K + (kt) + skol; \
            __builtin_amdgcn_global_load_lds(                                         \
                (__attribute__((address_space(1))) void*)gpb,                         \
                (__attribute__((address_space(3))) void*)&Bs[buf][(wave * 2 + j) * 512], \
                16, 0, 0);                                                            \
        }                                                                             \
    }

    // prologue: 3 stages in flight (12 per-wave VMEM ops)
    STAGE(0, kt0);
    STAGE(1, kt0 + 32);
    STAGE(2, kt0 + 64);

    int cur = 0;
#pragma unroll 1
    for (int kt = kt0; kt < ktend; kt += 32) {
        // wait ONLY the oldest stage's 4 loads (12 outstanding -> 8), then sync
        asm volatile("s_waitcnt vmcnt(8)\n\ts_barrier" ::: "memory");

        bf16x8 af[4], bfr[4];
#pragma unroll
        for (int mi = 0; mi < 4; ++mi)
            af[mi] = *reinterpret_cast<const bf16x8*>(&As[cur][(wm + mi * 16 + cidx) * 32 + sl8]);
#pragma unroll
        for (int ni = 0; ni < 4; ++ni)
            bfr[ni] = *reinterpret_cast<const bf16x8*>(&Bs[cur][(wn + ni * 16 + cidx) * 32 + sl8]);
#pragma unroll
        for (int mi = 0; mi < 4; ++mi)
#pragma unroll
            for (int ni = 0; ni < 4; ++ni)
                acc[mi][ni] = __builtin_amdgcn_mfma_f32_16x16x32_bf16(af[mi], bfr[ni], acc[mi][ni], 0, 0, 0);

        // all waves done READING buf cur (ds_reads completed before their MFMAs)
        asm volatile("s_barrier" ::: "memory");

        // re-stage buf cur for stage kt+96; tail stages a harmless dummy (kt0) so
        // the outstanding-load count stays exactly 12 -> vmcnt(8) above is exact
        int ktn = (kt + 96 < ktend) ? (kt + 96) : kt0;
        STAGE(cur, ktn);
        cur = (cur == 2) ? 0 : cur + 1;
    }
#undef STAGE

    u16* cbase = Cp + (size_t)z * M * N;
#pragma unroll
    for (int mi = 0; mi < 4; ++mi) {
#pragma unroll
        for (int r = 0; r < 4; ++r) {
            int row = bm + wm + mi * 16 + g * 4 + r;
            u16* cp = cbase + (size_t)row * N + bn + wn + cidx;
#pragma unroll
            for (int ni = 0; ni < 4; ++ni)
                cp[ni * 16] = f2bf(acc[mi][ni][r]);
        }
    }
}

// ---------------- sum two bf16 partials -> f32 ----------------
__global__ __launch_bounds__(256) void sum2_f32_k(const u16* __restrict__ a,
                                                  const u16* __restrict__ b,
                                                  float* __restrict__ out, int n8) {
    int i = blockIdx.x * 256 + threadIdx.x;
    if (i >= n8) return;
    u16x8 va = reinterpret_cast<const u16x8*>(a)[i];
    u16x8 vb = reinterpret_cast<const u16x8*>(b)[i];
    f32x4 lo, hi;
#pragma unroll
    for (int j = 0; j < 4; ++j) {
        lo[j] = bf2f(va[j]) + bf2f(vb[j]);
        hi[j] = bf2f(va[4 + j]) + bf2f(vb[4 + j]);
    }
    reinterpret_cast<f32x4*>(out)[i * 2] = lo;
    reinterpret_cast<f32x4*>(out)[i * 2 + 1] = hi;
}

// ---------------- RMSNorm + RoPE for Q and K heads (sums split-K partials) ----------------
// Q: pre-scaled by 0.125*log2(e) (exp2-base softmax), row-major [s][32*64]
// K: MFMA A-fragment order with PERMUTED key placement inside each 32-key group:
//   k32 -> phys (sub = bit2, row = (k32>>3)*4 + (k32&3)); this makes two QK 16-subs
//   concatenate into a K=32 PV B-fragment (lane g holds keys g*8..g*8+7).
__global__ __launch_bounds__(256) void norm_rope_k(const u16* __restrict__ p0,
                                                   const u16* __restrict__ p1,
                                                   const float* __restrict__ cosb,
                                                   const float* __restrict__ sinb,
                                                   const float* __restrict__ qw,
                                                   const float* __restrict__ kw,
                                                   u16* __restrict__ qn,
                                                   u16* __restrict__ kfrag) {
    int idx = blockIdx.x * 4 + (threadIdx.x >> 6);
    int lane = threadIdx.x & 63;
    int s = idx / 40, hh = idx - s * 40;
    size_t off = (hh < 32) ? ((size_t)s * 3072 + hh * 64 + lane)
                           : ((size_t)s * 3072 + 2048 + (hh - 32) * 64 + lane);
    float val = bf2f(p0[off]) + bf2f(p1[off]);
    float ss = val * val;
#pragma unroll
    for (int mm = 32; mm; mm >>= 1) ss += __shfl_xor(ss, mm);
    float w = (hh < 32) ? qw[lane] : kw[lane];
    float xn = val * rsqrtf(ss * (1.f / 64.f) + 1e-6f) * w;
    float part = __shfl_xor(xn, 32);
    float rot = (lane < 32) ? -part : part;
    float o = xn * cosb[s * 64 + lane] + rot * sinb[s * 64 + lane];
    if (hh < 32) {
        qn[(size_t)s * 2048 + hh * 64 + lane] = f2bf(o * (0.125f * LOG2E));
    } else {
        int h8 = hh - 32;
        int k32 = s & 31;
        int p32 = ((k32 >> 2) & 1) * 16 + ((k32 >> 3) << 2) + (k32 & 3);
        int p = (s & ~31) + p32;
        kfrag[(((size_t)h8 * 128 + (p >> 4)) << 10) + (lane >> 3) * 128 + (p & 15) * 8 + (lane & 7)] = f2bf(o);
    }
}

// ---------------- V in K=32 PV A-fragment order ----------------
// vfrag[kvh][kb32][dt][lane(g*16+cc)][i] = V[kb32*32 + g*8 + i][dt*16 + cc]
__global__ __launch_bounds__(256) void v_frag_k(const u16* __restrict__ p0,
                                                const u16* __restrict__ p1,
                                                u16* __restrict__ vfrag) {
    __shared__ float t[64][65];
    int s0 = blockIdx.x * 64;
    int h = blockIdx.y;
    int tx = threadIdx.x & 63, ty = threadIdx.x >> 6;
#pragma unroll
    for (int i = 0; i < 16; ++i) {
        int r = ty + i * 4;
        size_t off = (size_t)(s0 + r) * 3072 + 2560 + h * 64 + tx;
        t[r][tx] = bf2f(p0[off]) + bf2f(p1[off]);
    }
    __syncthreads();
    int dt = threadIdx.x >> 6, g = (threadIdx.x >> 4) & 3, cc = threadIdx.x & 15;
#pragma unroll
    for (int kb = 0; kb < 2; ++kb) {
        u16x8 o;
#pragma unroll
        for (int i = 0; i < 8; ++i) o[i] = f2bf(t[kb * 32 + g * 8 + i][dt * 16 + cc]);
        *reinterpret_cast<u16x8*>(
            &vfrag[((size_t)h * 64 + (s0 >> 5) + kb) * 2048 + dt * 512 + (size_t)(threadIdx.x & 63) * 8]) = o;
    }
}

// ---------------- Flash attention: 32 q-rows/wave, shared K/V, sequential streams ----------------
// 1-wave blocks; wave owns chunks c=2t (A) and c=2t+1 (B) over key-window w (512 keys,
// <=8 iterations). Per 64-key iteration: load K+V ONCE, then A's QK->softmax->PV
// followed by B's (sequential register lifetime; R9's interleaved version spilled).
// item -> (t,w): 160-item mapping; partial o (bf16) + l slots, merged by merge_k.
// NOTE: VGPR caps: (256,8)->32 regs spilled 1.3GB (R4); interleaved dual-stream ~190
// regs spilled (R9). Tripwire: FETCH/WRITE >> 30MB means spill.
__global__ __launch_bounds__(64, 3) void attn_k(const u16* __restrict__ qn,
                                                const u16* __restrict__ kfrag,
                                                const u16* __restrict__ vfrag,
                                                u16* __restrict__ obuf,
                                                float* __restrict__ lbuf) {
    int h = blockIdx.x;
    int kvh = h >> 2;
    int lane = threadIdx.x;
    int item = 159 - blockIdx.y;   // reversed: 4-window pairs (most iters) first
    int t, w;
    if (item < 16)      { t = item;                    w = 0; }
    else if (item < 48) { t = 16 + ((item - 16) >> 1); w = (item - 16) & 1; }
    else if (item < 96) { int r = item - 48; int q = r / 3; t = 32 + q; w = r - 3 * q; }
    else                { t = 48 + ((item - 96) >> 2); w = (item - 96) & 3; }

    int qA0 = t * 32;          // chunk 2t   rows [qA0, qA0+16)
    int qB0 = qA0 + 16;        // chunk 2t+1 rows [qB0, qB0+16)
    int kv0 = w * 512;
    int nkA = qA0 + 16, nkB = qB0 + 16;
    int kvend = (kv0 + 512 < nkB) ? (kv0 + 512) : nkB;

    int g = lane >> 4, cc = lane & 15;
    int qrowA = qA0 + cc, qrowB = qB0 + cc;

    const size_t qoffA = (size_t)qrowA * 2048 + h * 64;
    const size_t qoffB = (size_t)qrowB * 2048 + h * 64;
    bf16x8 qa0 = *reinterpret_cast<const bf16x8*>(&qn[qoffA + g * 8]);
    bf16x8 qa1 = *reinterpret_cast<const bf16x8*>(&qn[qoffA + 32 + g * 8]);
    bf16x8 qb0 = *reinterpret_cast<const bf16x8*>(&qn[qoffB + g * 8]);
    bf16x8 qb1 = *reinterpret_cast<const bf16x8*>(&qn[qoffB + 32 + g * 8]);

    float lA = 0.f, lB = 0.f;
    f32x4 oA[4] = {}, oB[4] = {};

    const u16* kbase = kfrag + (((size_t)kvh * 128) << 10) + lane * 8;
    const u16* vbase = vfrag + (size_t)kvh * 64 * 2048 + lane * 8;

#pragma unroll 1
    for (; kv0 < kvend; kv0 += 64) {
        // K + V loads for this block (one set, shared by both streams)
        bf16x8 kf0[4], kf1[4], vv[2][4];
#pragma unroll
        for (int sub = 0; sub < 4; ++sub) {
            const u16* kp = kbase + (size_t)((kv0 >> 4) + sub) * 1024;
            kf0[sub] = *reinterpret_cast<const bf16x8*>(kp);
            kf1[sub] = *reinterpret_cast<const bf16x8*>(kp + 512);
        }
#pragma unroll
        for (int sp = 0; sp < 2; ++sp)
#pragma unroll
            for (int dt = 0; dt < 4; ++dt)
                vv[sp][dt] = *reinterpret_cast<const bf16x8*>(
                    vbase + (size_t)((kv0 >> 5) + sp) * 2048 + dt * 512);

        bool doA = kv0 < nkA;   // wave-uniform: A's range is 32 keys shorter

        // ---- stream A (st/pb live only in this span) ----
        if (doA) {
            f32x4 st[4];
            __builtin_amdgcn_s_setprio(1);
#pragma unroll
            for (int sub = 0; sub < 4; ++sub) {
                st[sub] = __builtin_amdgcn_mfma_f32_16x16x32_bf16(kf0[sub], qa0, (f32x4){0.f, 0.f, 0.f, 0.f}, 0, 0, 0);
                st[sub] = __builtin_amdgcn_mfma_f32_16x16x32_bf16(kf1[sub], qa1, st[sub], 0, 0, 0);
            }
            __builtin_amdgcn_s_setprio(0);
            if (kv0 + 64 > qA0) {
#pragma unroll
                for (int sub = 0; sub < 4; ++sub)
#pragma unroll
                    for (int r = 0; r < 4; ++r) {
                        int key = kv0 + (sub >> 1) * 32 + g * 8 + (sub & 1) * 4 + r;
                        if (key > qrowA) st[sub][r] = -1e30f;
                    }
            }
            u16x8 pb[2];
            float rs = 0.f;
#pragma unroll
            for (int sub = 0; sub < 4; ++sub)
#pragma unroll
                for (int r = 0; r < 4; ++r) {
                    float e = __builtin_amdgcn_exp2f(st[sub][r]);
                    rs += e;
                    pb[sub >> 1][(sub & 1) * 4 + r] = f2bf(e);
                }
            lA += rs;
            __builtin_amdgcn_s_setprio(1);
#pragma unroll
            for (int sp = 0; sp < 2; ++sp) {
                bf16x8 pbb = __builtin_bit_cast(bf16x8, pb[sp]);
#pragma unroll
                for (int dt = 0; dt < 4; ++dt)
                    oA[dt] = __builtin_amdgcn_mfma_f32_16x16x32_bf16(vv[sp][dt], pbb, oA[dt], 0, 0, 0);
            }
            __builtin_amdgcn_s_setprio(0);
        }

        // ---- stream B ----
        {
            f32x4 st[4];
            __builtin_amdgcn_s_setprio(1);
#pragma unroll
            for (int sub = 0; sub < 4; ++sub) {
                st[sub] = __builtin_amdgcn_mfma_f32_16x16x32_bf16(kf0[sub], qb0, (f32x4){0.f, 0.f, 0.f, 0.f}, 0, 0, 0);
                st[sub] = __builtin_amdgcn_mfma_f32_16x16x32_bf16(kf1[sub], qb1, st[sub], 0, 0, 0);
            }
            __builtin_amdgcn_s_setprio(0);
            if (kv0 + 64 > qB0) {
#pragma unroll
                for (int sub = 0; sub < 4; ++sub)
#pragma unroll
                    for (int r = 0; r < 4; ++r) {
                        int key = kv0 + (sub >> 1) * 32 + g * 8 + (sub & 1) * 4 + r;
                        if (key > qrowB) st[sub][r] = -1e30f;
                    }
            }
            u16x8 pb[2];
            float rs = 0.f;
#pragma unroll
            for (int sub = 0; sub < 4; ++sub)
#pragma unroll
                for (int r = 0; r < 4; ++r) {
                    float e = __builtin_amdgcn_exp2f(st[sub][r]);
                    rs += e;
                    pb[sub >> 1][(sub & 1) * 4 + r] = f2bf(e);
                }
            lB += rs;
            __builtin_amdgcn_s_setprio(1);
#pragma unroll
            for (int sp = 0; sp < 2; ++sp) {
                bf16x8 pbb = __builtin_bit_cast(bf16x8, pb[sp]);
#pragma unroll
                for (int dt = 0; dt < 4; ++dt)
                    oB[dt] = __builtin_amdgcn_mfma_f32_16x16x32_bf16(vv[sp][dt], pbb, oB[dt], 0, 0, 0);
            }
            __builtin_amdgcn_s_setprio(0);
        }
    }

    // private-slot partial writes (plain stores, no atomics); slot = (h*160+item)*2+half
    lA += __shfl_xor(lA, 16);
    lA += __shfl_xor(lA, 32);
    lB += __shfl_xor(lB, 16);
    lB += __shfl_xor(lB, 32);
    size_t slotA = ((size_t)h * 160 + item) * 2;
    if (lane < 16) {
        lbuf[slotA * 16 + cc] = lA;
        lbuf[(slotA + 1) * 16 + cc] = lB;
    }
    u16* spA = obuf + slotA * 1024;
    u16* spB = obuf + (slotA + 1) * 1024;
#pragma unroll
    for (int dt = 0; dt < 4; ++dt) {
        u16x4 ovA, ovB;
#pragma unroll
        for (int r = 0; r < 4; ++r) {
            ovA[r] = f2bf(oA[dt][r]);
            ovB[r] = f2bf(oB[dt][r]);
        }
        *reinterpret_cast<u16x4*>(&spA[cc * 64 + dt * 16 + g * 4]) = ovA;
        *reinterpret_cast<u16x4*>(&spB[cc * 64 + dt * 16 + g * 4]) = ovB;
    }
}

// ---------------- merge: attn_bf16 = sum(o_w) / (sum(l_w) + 2^(sink*log2e)) ----------------
__global__ __launch_bounds__(256) void merge_k(const u16* __restrict__ obuf,
                                               const float* __restrict__ lbuf,
                                               const float* __restrict__ sink,
                                               u16* __restrict__ attnb) {
    int row = blockIdx.x;
    int c = row >> 4, cc = row & 15;
    int t2 = c >> 1, half = c & 1;
    int nw = (t2 >> 4) + 1;  // windows for this 32-row pair
    int jb = (t2 < 16) ? t2
           : (t2 < 32) ? 16 + ((t2 - 16) << 1)
           : (t2 < 48) ? 48 + 3 * (t2 - 32)
                       : 96 + ((t2 - 48) << 2);
    int t = threadIdx.x;
    int h = t >> 3, col0 = (t & 7) * 8;

    float acc[8] = {};
    float lsum = __builtin_amdgcn_exp2f(sink[h] * LOG2E);
#pragma unroll 1
    for (int w = 0; w < nw; ++w) {
        size_t slot = ((size_t)h * 160 + jb + w) * 2 + half;
        lsum += lbuf[slot * 16 + cc];
        u16x8 v = *reinterpret_cast<const u16x8*>(&obuf[slot * 1024 + cc * 64 + col0]);
#pragma unroll
        for (int i = 0; i < 8; ++i) acc[i] += bf2f(v[i]);
    }
    float inv = 1.f / lsum;
    u16x8 ob;
#pragma unroll
    for (int i = 0; i < 8; ++i) ob[i] = f2bf(acc[i] * inv);
    *reinterpret_cast<u16x8*>(&attnb[(size_t)row * 2048 + h * 64 + col0]) = ob;
}

extern "C" void kernel_launch(void* const* d_in, const int* in_sizes, int n_in,
                              void* d_out, int out_size, void* d_ws, size_t ws_size,
                              hipStream_t stream) {
    const float* x    = (const float*)d_in[0];
    const float* cosb = (const float*)d_in[2];
    const float* sinb = (const float*)d_in[3];
    const float* wq   = (const float*)d_in[4];
    const float* wk   = (const float*)d_in[5];
    const float* wv   = (const float*)d_in[6];
    const float* wo   = (const float*)d_in[7];
    const float* qw   = (const float*)d_in[8];
    const float* kw   = (const float*)d_in[9];
    const float* sink = (const float*)d_in[10];
    float* out = (float*)d_out;

    char* ws = (char*)d_ws;
    size_t off = 0;
    auto alloc = [&](size_t bytes) {
        char* p = ws + off;
        off += (bytes + 255) & ~(size_t)255;
        return p;
    };
    u16*   xb    = (u16*)alloc((size_t)2048 * 2048 * 2);       // x bf16
    u16*   wqkvt = (u16*)alloc((size_t)3072 * 2048 * 2);       // [wq^T; wk^T; wv^T]
    u16*   wot   = (u16*)alloc((size_t)2048 * 2048 * 2);       // wo^T
    u16*   p0    = (u16*)alloc((size_t)2048 * 3072 * 2);       // GEMM1 partial z=0 (bf16)
    u16*   p1    = (u16*)alloc((size_t)2048 * 3072 * 2);       // GEMM1 partial z=1 (bf16)
    u16*   qnb   = (u16*)alloc((size_t)2048 * 2048 * 2);
    u16*   kfrag = (u16*)alloc((size_t)8 * 128 * 1024 * 2);
    u16*   vfrag = (u16*)alloc((size_t)8 * 64 * 2048 * 2);
    float* lbuf  = (float*)alloc((size_t)32 * 320 * 16 * 4);
    u16*   attnb = xb;        // xb dead after GEMM1
    u16*   obuf  = p0;        // p0+p1 (25.2 MB contiguous) dead after norm_rope/v_frag; obuf needs 21 MB
    u16*   o2p   = p0;        // obuf dead after merge_k; GEMM2 bf16 partials need 16.8 MB

    cast_bf16_k<<<2048, 256, 0, stream>>>(x, xb, 2048 * 2048 / 4);
    transpose_cast_k<<<dim3(32, 32), 256, 0, stream>>>(wq, wqkvt, 2048, 2048);
    transpose_cast_k<<<dim3(8, 32), 256, 0, stream>>>(wk, wqkvt + (size_t)2048 * 2048, 2048, 512);
    transpose_cast_k<<<dim3(8, 32), 256, 0, stream>>>(wv, wqkvt + (size_t)2560 * 2048, 2048, 512);
    transpose_cast_k<<<dim3(32, 32), 256, 0, stream>>>(wo, wot, 2048, 2048);

    gemm_bt_dbuf_k<<<dim3(24, 16, 2), 256, 0, stream>>>(xb, wqkvt, p0, 2048, 3072, 2048);
    norm_rope_k<<<20480, 256, 0, stream>>>(p0, p1, cosb, sinb, qw, kw, qnb, kfrag);
    v_frag_k<<<dim3(32, 8), 256, 0, stream>>>(p0, p1, vfrag);

    attn_k<<<dim3(32, 160), 64, 0, stream>>>(qnb, kfrag, vfrag, obuf, lbuf);
    merge_k<<<2048, 256, 0, stream>>>(obuf, lbuf, sink, attnb);

    gemm_bt_dbuf_k<<<dim3(16, 16, 2), 256, 0, stream>>>(attnb, wot, o2p, 2048, 2048, 2048);
    sum2_f32_k<<<2048, 256, 0, stream>>>(o2p, o2p + (size_t)2048 * 2048, out, 2048 * 2048 / 8);
}

// Round 15
// 140.726 us; speedup vs baseline: 1.1268x; 1.0495x over previous
//
#include <hip/hip_runtime.h>

typedef unsigned short u16;
typedef __bf16 bf16;
typedef float f32x4 __attribute__((ext_vector_type(4)));
typedef bf16 bf16x8 __attribute__((ext_vector_type(8)));
typedef short s16x4 __attribute__((ext_vector_type(4)));
typedef u16 u16x4 __attribute__((ext_vector_type(4)));
typedef u16 u16x8 __attribute__((ext_vector_type(8)));

#define SEQ 2048
#define LOG2E 1.4426950408889634f

__device__ __forceinline__ u16 f2bf(float f) {
    return __builtin_bit_cast(u16, (bf16)f);
}
__device__ __forceinline__ float bf2f(u16 u) {
    unsigned int w = ((unsigned int)u) << 16;
    return __builtin_bit_cast(float, w);
}

// ---------------- cast f32 -> bf16 (vectorized) ----------------
__global__ __launch_bounds__(256) void cast_bf16_k(const float* __restrict__ in,
                                                   u16* __restrict__ out, int n4) {
    int i = blockIdx.x * 256 + threadIdx.x;
    int stride = gridDim.x * 256;
    for (; i < n4; i += stride) {
        float4 v = reinterpret_cast<const float4*>(in)[i];
        u16x4 o;
        o[0] = f2bf(v.x); o[1] = f2bf(v.y); o[2] = f2bf(v.z); o[3] = f2bf(v.w);
        reinterpret_cast<u16x4*>(out)[i] = o;
    }
}

// ---------------- fused transpose + cast for all 4 weights (one launch) ----------------
// blocks [0,1024): wq->wqkvt rows 0..2048   [1024,1280): wk->rows 2048..2560
// [1280,1536): wv->rows 2560..3072          [1536,2560): wo->wot
__global__ __launch_bounds__(256) void transpose_all_k(const float* __restrict__ wq,
                                                       const float* __restrict__ wk,
                                                       const float* __restrict__ wv,
                                                       const float* __restrict__ wo,
                                                       u16* __restrict__ wqkvt,
                                                       u16* __restrict__ wot) {
    __shared__ float t[64][65];
    int b = blockIdx.x;
    const float* src;
    u16* dst;
    int C, bx, by;
    if (b < 1024)      { src = wq; dst = wqkvt;                         C = 2048; bx = b & 31; by = b >> 5; }
    else if (b < 1280) { b -= 1024; src = wk; dst = wqkvt + (size_t)2048 * 2048; C = 512;  bx = b & 7;  by = b >> 3; }
    else if (b < 1536) { b -= 1280; src = wv; dst = wqkvt + (size_t)2560 * 2048; C = 512;  bx = b & 7;  by = b >> 3; }
    else               { b -= 1536; src = wo; dst = wot;                C = 2048; bx = b & 31; by = b >> 5; }
    int c0 = bx * 64, r0 = by * 64;   // src rows are always 2048 (R = 2048)
    int tx = threadIdx.x & 63, ty = threadIdx.x >> 6;
#pragma unroll
    for (int i = 0; i < 16; ++i) {
        int r = ty + i * 4;
        t[r][tx] = src[(size_t)(r0 + r) * C + c0 + tx];
    }
    __syncthreads();
#pragma unroll
    for (int i = 0; i < 16; ++i) {
        int c = ty + i * 4;
        dst[(size_t)(c0 + c) * 2048 + r0 + tx] = f2bf(t[tx][c]);
    }
}

// ---------------- GEMM partial: Cp[z][M,N](bf16) = A[M,kz] @ Bt[N,kz]^T ----------------
// 128x128 tile, BK=32, split-K=2, double-buffered LDS with prefetch (R12-best body),
// + bijective XCD swizzle (T1): nwg%8==0 for our grids; each XCD gets a CONTIGUOUS
// chunk of work IDs = 4 consecutive bm-panels x all bn x one z -> A-slice (2MB) is
// L2-resident per XCD (R14 counters: FETCH 41MB vs 21MB working set = 2x overfetch
// from round-robin XCD dispatch).
// XOR-swizzled LDS slots (pre-swizzled gload_lds source + swizzled ds_read; rule #21).
__global__ __launch_bounds__(256) void gemm_bt_dbuf_k(const u16* __restrict__ A,
                                                      const u16* __restrict__ Bt,
                                                      u16* __restrict__ Cp,
                                                      int M, int N, int K) {
    __shared__ __align__(16) u16 As[2][128 * 32];
    __shared__ __align__(16) u16 Bs[2][128 * 32];
    int tid = threadIdx.x;
    int wave = tid >> 6, lane = tid & 63;

    // XCD-aware bijective work remap
    unsigned nx = gridDim.x, ny = gridDim.y;
    unsigned nwg = nx * ny * gridDim.z;
    unsigned id = blockIdx.x + nx * (blockIdx.y + ny * blockIdx.z);
    unsigned qq = nwg >> 3;
    unsigned swz = (id & 7) * qq + (id >> 3);
    unsigned bxw = swz % nx;
    unsigned rem = swz / nx;
    unsigned byw = rem % ny;
    unsigned bzw = rem / ny;
    int bm = byw * 128, bn = bxw * 128;
    int z = bzw;

    int kslice = K / gridDim.z;
    int kt0 = z * kslice, ktend = kt0 + kslice;
    int wm = (wave >> 1) * 64, wn = (wave & 1) * 64;
    int g = lane >> 4, cidx = lane & 15;
    f32x4 acc[4][4] = {};

    // staging: LDS slot (srow, lane&3) holds global k-chunk (lane&3) ^ ((srow>>1)&3)
    int srow = lane >> 2;
    int skol = ((lane & 3) ^ ((srow >> 1) & 3)) * 8;
    // read: logical chunk g of row r lives at slot g ^ ((r_in16>>1)&3); r_in16 = cidx
    int sl8 = (g ^ ((cidx >> 1) & 3)) * 8;

#define STAGE(buf, kt)                                                                \
    {                                                                                 \
        _Pragma("unroll")                                                             \
        for (int j = 0; j < 2; ++j) {                                                 \
            const u16* gpa = A + (size_t)(bm + (wave * 2 + j) * 16 + srow) * K + (kt) + skol; \
            __builtin_amdgcn_global_load_lds(                                         \
                (__attribute__((address_space(1))) void*)gpa,                         \
                (__attribute__((address_space(3))) void*)&As[buf][(wave * 2 + j) * 512], \
                16, 0, 0);                                                            \
        }                                                                             \
        _Pragma("unroll")                                                             \
        for (int j = 0; j < 2; ++j) {                                                 \
            const u16* gpb = Bt + (size_t)(bn + (wave * 2 + j) * 16 + srow) * K + (kt) + skol; \
            __builtin_amdgcn_global_load_lds(                                         \
                (__attribute__((address_space(1))) void*)gpb,                         \
                (__attribute__((address_space(3))) void*)&Bs[buf][(wave * 2 + j) * 512], \
                16, 0, 0);                                                            \
        }                                                                             \
    }

    STAGE(0, kt0);
    asm volatile("s_waitcnt vmcnt(0)" ::: "memory");
    __syncthreads();

    int cur = 0;
#pragma unroll 1
    for (int kt = kt0; kt < ktend; kt += 32) {
        if (kt + 32 < ktend) STAGE(cur ^ 1, kt + 32);  // prefetch in flight across compute

        bf16x8 af[4], bfr[4];
#pragma unroll
        for (int mi = 0; mi < 4; ++mi)
            af[mi] = *reinterpret_cast<const bf16x8*>(&As[cur][(wm + mi * 16 + cidx) * 32 + sl8]);
#pragma unroll
        for (int ni = 0; ni < 4; ++ni)
            bfr[ni] = *reinterpret_cast<const bf16x8*>(&Bs[cur][(wn + ni * 16 + cidx) * 32 + sl8]);
#pragma unroll
        for (int mi = 0; mi < 4; ++mi)
#pragma unroll
            for (int ni = 0; ni < 4; ++ni)
                acc[mi][ni] = __builtin_amdgcn_mfma_f32_16x16x32_bf16(af[mi], bfr[ni], acc[mi][ni], 0, 0, 0);

        asm volatile("s_waitcnt vmcnt(0)" ::: "memory");
        __syncthreads();
        cur ^= 1;
    }
#undef STAGE

    u16* cbase = Cp + (size_t)z * M * N;
#pragma unroll
    for (int mi = 0; mi < 4; ++mi) {
#pragma unroll
        for (int r = 0; r < 4; ++r) {
            int row = bm + wm + mi * 16 + g * 4 + r;
            u16* cp = cbase + (size_t)row * N + bn + wn + cidx;
#pragma unroll
            for (int ni = 0; ni < 4; ++ni)
                cp[ni * 16] = f2bf(acc[mi][ni][r]);
        }
    }
}

// ---------------- sum two bf16 partials -> f32 ----------------
__global__ __launch_bounds__(256) void sum2_f32_k(const u16* __restrict__ a,
                                                  const u16* __restrict__ b,
                                                  float* __restrict__ out, int n8) {
    int i = blockIdx.x * 256 + threadIdx.x;
    if (i >= n8) return;
    u16x8 va = reinterpret_cast<const u16x8*>(a)[i];
    u16x8 vb = reinterpret_cast<const u16x8*>(b)[i];
    f32x4 lo, hi;
#pragma unroll
    for (int j = 0; j < 4; ++j) {
        lo[j] = bf2f(va[j]) + bf2f(vb[j]);
        hi[j] = bf2f(va[4 + j]) + bf2f(vb[4 + j]);
    }
    reinterpret_cast<f32x4*>(out)[i * 2] = lo;
    reinterpret_cast<f32x4*>(out)[i * 2 + 1] = hi;
}

// ---------------- RMSNorm + RoPE for Q and K heads (sums split-K partials) ----------------
// Q: pre-scaled by 0.125*log2(e) (exp2-base softmax), row-major [s][32*64]
// K: MFMA A-fragment order with PERMUTED key placement inside each 32-key group:
//   k32 -> phys (sub = bit2, row = (k32>>3)*4 + (k32&3)); this makes two QK 16-subs
//   concatenate into a K=32 PV B-fragment (lane g holds keys g*8..g*8+7).
__global__ __launch_bounds__(256) void norm_rope_k(const u16* __restrict__ p0,
                                                   const u16* __restrict__ p1,
                                                   const float* __restrict__ cosb,
                                                   const float* __restrict__ sinb,
                                                   const float* __restrict__ qw,
                                                   const float* __restrict__ kw,
                                                   u16* __restrict__ qn,
                                                   u16* __restrict__ kfrag) {
    int idx = blockIdx.x * 4 + (threadIdx.x >> 6);
    int lane = threadIdx.x & 63;
    int s = idx / 40, hh = idx - s * 40;
    size_t off = (hh < 32) ? ((size_t)s * 3072 + hh * 64 + lane)
                           : ((size_t)s * 3072 + 2048 + (hh - 32) * 64 + lane);
    float val = bf2f(p0[off]) + bf2f(p1[off]);
    float ss = val * val;
#pragma unroll
    for (int mm = 32; mm; mm >>= 1) ss += __shfl_xor(ss, mm);
    float w = (hh < 32) ? qw[lane] : kw[lane];
    float xn = val * rsqrtf(ss * (1.f / 64.f) + 1e-6f) * w;
    float part = __shfl_xor(xn, 32);
    float rot = (lane < 32) ? -part : part;
    float o = xn * cosb[s * 64 + lane] + rot * sinb[s * 64 + lane];
    if (hh < 32) {
        qn[(size_t)s * 2048 + hh * 64 + lane] = f2bf(o * (0.125f * LOG2E));
    } else {
        int h8 = hh - 32;
        int k32 = s & 31;
        int p32 = ((k32 >> 2) & 1) * 16 + ((k32 >> 3) << 2) + (k32 & 3);
        int p = (s & ~31) + p32;
        kfrag[(((size_t)h8 * 128 + (p >> 4)) << 10) + (lane >> 3) * 128 + (p & 15) * 8 + (lane & 7)] = f2bf(o);
    }
}

// ---------------- V in K=32 PV A-fragment order ----------------
// vfrag[kvh][kb32][dt][lane(g*16+cc)][i] = V[kb32*32 + g*8 + i][dt*16 + cc]
__global__ __launch_bounds__(256) void v_frag_k(const u16* __restrict__ p0,
                                                const u16* __restrict__ p1,
                                                u16* __restrict__ vfrag) {
    __shared__ float t[64][65];
    int s0 = blockIdx.x * 64;
    int h = blockIdx.y;
    int tx = threadIdx.x & 63, ty = threadIdx.x >> 6;
#pragma unroll
    for (int i = 0; i < 16; ++i) {
        int r = ty + i * 4;
        size_t off = (size_t)(s0 + r) * 3072 + 2560 + h * 64 + tx;
        t[r][tx] = bf2f(p0[off]) + bf2f(p1[off]);
    }
    __syncthreads();
    int dt = threadIdx.x >> 6, g = (threadIdx.x >> 4) & 3, cc = threadIdx.x & 15;
#pragma unroll
    for (int kb = 0; kb < 2; ++kb) {
        u16x8 o;
#pragma unroll
        for (int i = 0; i < 8; ++i) o[i] = f2bf(t[kb * 32 + g * 8 + i][dt * 16 + cc]);
        *reinterpret_cast<u16x8*>(
            &vfrag[((size_t)h * 64 + (s0 >> 5) + kb) * 2048 + dt * 512 + (size_t)(threadIdx.x & 63) * 8]) = o;
    }
}

// ---------------- Flash attention: 32 q-rows/wave, shared K/V, sequential streams ----------------
// 1-wave blocks; wave owns chunks c=2t (A) and c=2t+1 (B) over key-window w (512 keys,
// <=8 iterations). Per 64-key iteration: load K+V ONCE, then A's QK->softmax->PV
// followed by B's (sequential register lifetime; R9's interleaved version spilled).
// item -> (t,w): 160-item mapping; partial o (bf16) + l slots, merged by merge_k.
// NOTE: VGPR caps: (256,8)->32 regs spilled 1.3GB (R4); interleaved dual-stream ~190
// regs spilled (R9). Tripwire: FETCH/WRITE >> 30MB means spill.
__global__ __launch_bounds__(64, 3) void attn_k(const u16* __restrict__ qn,
                                                const u16* __restrict__ kfrag,
                                                const u16* __restrict__ vfrag,
                                                u16* __restrict__ obuf,
                                                float* __restrict__ lbuf) {
    int h = blockIdx.x;
    int kvh = h >> 2;
    int lane = threadIdx.x;
    int item = 159 - blockIdx.y;   // reversed: 4-window pairs (most iters) first
    int t, w;
    if (item < 16)      { t = item;                    w = 0; }
    else if (item < 48) { t = 16 + ((item - 16) >> 1); w = (item - 16) & 1; }
    else if (item < 96) { int r = item - 48; int q = r / 3; t = 32 + q; w = r - 3 * q; }
    else                { t = 48 + ((item - 96) >> 2); w = (item - 96) & 3; }

    int qA0 = t * 32;          // chunk 2t   rows [qA0, qA0+16)
    int qB0 = qA0 + 16;        // chunk 2t+1 rows [qB0, qB0+16)
    int kv0 = w * 512;
    int nkA = qA0 + 16, nkB = qB0 + 16;
    int kvend = (kv0 + 512 < nkB) ? (kv0 + 512) : nkB;

    int g = lane >> 4, cc = lane & 15;
    int qrowA = qA0 + cc, qrowB = qB0 + cc;

    const size_t qoffA = (size_t)qrowA * 2048 + h * 64;
    const size_t qoffB = (size_t)qrowB * 2048 + h * 64;
    bf16x8 qa0 = *reinterpret_cast<const bf16x8*>(&qn[qoffA + g * 8]);
    bf16x8 qa1 = *reinterpret_cast<const bf16x8*>(&qn[qoffA + 32 + g * 8]);
    bf16x8 qb0 = *reinterpret_cast<const bf16x8*>(&qn[qoffB + g * 8]);
    bf16x8 qb1 = *reinterpret_cast<const bf16x8*>(&qn[qoffB + 32 + g * 8]);

    float lA = 0.f, lB = 0.f;
    f32x4 oA[4] = {}, oB[4] = {};

    const u16* kbase = kfrag + (((size_t)kvh * 128) << 10) + lane * 8;
    const u16* vbase = vfrag + (size_t)kvh * 64 * 2048 + lane * 8;

#pragma unroll 1
    for (; kv0 < kvend; kv0 += 64) {
        // K + V loads for this block (one set, shared by both streams)
        bf16x8 kf0[4], kf1[4], vv[2][4];
#pragma unroll
        for (int sub = 0; sub < 4; ++sub) {
            const u16* kp = kbase + (size_t)((kv0 >> 4) + sub) * 1024;
            kf0[sub] = *reinterpret_cast<const bf16x8*>(kp);
            kf1[sub] = *reinterpret_cast<const bf16x8*>(kp + 512);
        }
#pragma unroll
        for (int sp = 0; sp < 2; ++sp)
#pragma unroll
            for (int dt = 0; dt < 4; ++dt)
                vv[sp][dt] = *reinterpret_cast<const bf16x8*>(
                    vbase + (size_t)((kv0 >> 5) + sp) * 2048 + dt * 512);

        bool doA = kv0 < nkA;   // wave-uniform: A's range is 32 keys shorter

        // ---- stream A (st/pb live only in this span) ----
        if (doA) {
            f32x4 st[4];
            __builtin_amdgcn_s_setprio(1);
#pragma unroll
            for (int sub = 0; sub < 4; ++sub) {
                st[sub] = __builtin_amdgcn_mfma_f32_16x16x32_bf16(kf0[sub], qa0, (f32x4){0.f, 0.f, 0.f, 0.f}, 0, 0, 0);
                st[sub] = __builtin_amdgcn_mfma_f32_16x16x32_bf16(kf1[sub], qa1, st[sub], 0, 0, 0);
            }
            __builtin_amdgcn_s_setprio(0);
            if (kv0 + 64 > qA0) {
#pragma unroll
                for (int sub = 0; sub < 4; ++sub)
#pragma unroll
                    for (int r = 0; r < 4; ++r) {
                        int key = kv0 + (sub >> 1) * 32 + g * 8 + (sub & 1) * 4 + r;
                        if (key > qrowA) st[sub][r] = -1e30f;
                    }
            }
            u16x8 pb[2];
            float rs = 0.f;
#pragma unroll
            for (int sub = 0; sub < 4; ++sub)
#pragma unroll
                for (int r = 0; r < 4; ++r) {
                    float e = __builtin_amdgcn_exp2f(st[sub][r]);
                    rs += e;
                    pb[sub >> 1][(sub & 1) * 4 + r] = f2bf(e);
                }
            lA += rs;
            __builtin_amdgcn_s_setprio(1);
#pragma unroll
            for (int sp = 0; sp < 2; ++sp) {
                bf16x8 pbb = __builtin_bit_cast(bf16x8, pb[sp]);
#pragma unroll
                for (int dt = 0; dt < 4; ++dt)
                    oA[dt] = __builtin_amdgcn_mfma_f32_16x16x32_bf16(vv[sp][dt], pbb, oA[dt], 0, 0, 0);
            }
            __builtin_amdgcn_s_setprio(0);
        }

        // ---- stream B ----
        {
            f32x4 st[4];
            __builtin_amdgcn_s_setprio(1);
#pragma unroll
            for (int sub = 0; sub < 4; ++sub) {
                st[sub] = __builtin_amdgcn_mfma_f32_16x16x32_bf16(kf0[sub], qb0, (f32x4){0.f, 0.f, 0.f, 0.f}, 0, 0, 0);
                st[sub] = __builtin_amdgcn_mfma_f32_16x16x32_bf16(kf1[sub], qb1, st[sub], 0, 0, 0);
            }
            __builtin_amdgcn_s_setprio(0);
            if (kv0 + 64 > qB0) {
#pragma unroll
                for (int sub = 0; sub < 4; ++sub)
#pragma unroll
                    for (int r = 0; r < 4; ++r) {
                        int key = kv0 + (sub >> 1) * 32 + g * 8 + (sub & 1) * 4 + r;
                        if (key > qrowB) st[sub][r] = -1e30f;
                    }
            }
            u16x8 pb[2];
            float rs = 0.f;
#pragma unroll
            for (int sub = 0; sub < 4; ++sub)
#pragma unroll
                for (int r = 0; r < 4; ++r) {
                    float e = __builtin_amdgcn_exp2f(st[sub][r]);
                    rs += e;
                    pb[sub >> 1][(sub & 1) * 4 + r] = f2bf(e);
                }
            lB += rs;
            __builtin_amdgcn_s_setprio(1);
#pragma unroll
            for (int sp = 0; sp < 2; ++sp) {
                bf16x8 pbb = __builtin_bit_cast(bf16x8, pb[sp]);
#pragma unroll
                for (int dt = 0; dt < 4; ++dt)
                    oB[dt] = __builtin_amdgcn_mfma_f32_16x16x32_bf16(vv[sp][dt], pbb, oB[dt], 0, 0, 0);
            }
            __builtin_amdgcn_s_setprio(0);
        }
    }

    // private-slot partial writes (plain stores, no atomics); slot = (h*160+item)*2+half
    lA += __shfl_xor(lA, 16);
    lA += __shfl_xor(lA, 32);
    lB += __shfl_xor(lB, 16);
    lB += __shfl_xor(lB, 32);
    size_t slotA = ((size_t)h * 160 + item) * 2;
    if (lane < 16) {
        lbuf[slotA * 16 + cc] = lA;
        lbuf[(slotA + 1) * 16 + cc] = lB;
    }
    u16* spA = obuf + slotA * 1024;
    u16* spB = obuf + (slotA + 1) * 1024;
#pragma unroll
    for (int dt = 0; dt < 4; ++dt) {
        u16x4 ovA, ovB;
#pragma unroll
        for (int r = 0; r < 4; ++r) {
            ovA[r] = f2bf(oA[dt][r]);
            ovB[r] = f2bf(oB[dt][r]);
        }
        *reinterpret_cast<u16x4*>(&spA[cc * 64 + dt * 16 + g * 4]) = ovA;
        *reinterpret_cast<u16x4*>(&spB[cc * 64 + dt * 16 + g * 4]) = ovB;
    }
}

// ---------------- merge: attn_bf16 = sum(o_w) / (sum(l_w) + 2^(sink*log2e)) ----------------
__global__ __launch_bounds__(256) void merge_k(const u16* __restrict__ obuf,
                                               const float* __restrict__ lbuf,
                                               const float* __restrict__ sink,
                                               u16* __restrict__ attnb) {
    int row = blockIdx.x;
    int c = row >> 4, cc = row & 15;
    int t2 = c >> 1, half = c & 1;
    int nw = (t2 >> 4) + 1;  // windows for this 32-row pair
    int jb = (t2 < 16) ? t2
           : (t2 < 32) ? 16 + ((t2 - 16) << 1)
           : (t2 < 48) ? 48 + 3 * (t2 - 32)
                       : 96 + ((t2 - 48) << 2);
    int t = threadIdx.x;
    int h = t >> 3, col0 = (t & 7) * 8;

    float acc[8] = {};
    float lsum = __builtin_amdgcn_exp2f(sink[h] * LOG2E);
#pragma unroll 1
    for (int w = 0; w < nw; ++w) {
        size_t slot = ((size_t)h * 160 + jb + w) * 2 + half;
        lsum += lbuf[slot * 16 + cc];
        u16x8 v = *reinterpret_cast<const u16x8*>(&obuf[slot * 1024 + cc * 64 + col0]);
#pragma unroll
        for (int i = 0; i < 8; ++i) acc[i] += bf2f(v[i]);
    }
    float inv = 1.f / lsum;
    u16x8 ob;
#pragma unroll
    for (int i = 0; i < 8; ++i) ob[i] = f2bf(acc[i] * inv);
    *reinterpret_cast<u16x8*>(&attnb[(size_t)row * 2048 + h * 64 + col0]) = ob;
}

extern "C" void kernel_launch(void* const* d_in, const int* in_sizes, int n_in,
                              void* d_out, int out_size, void* d_ws, size_t ws_size,
                              hipStream_t stream) {
    const float* x    = (const float*)d_in[0];
    const float* cosb = (const float*)d_in[2];
    const float* sinb = (const float*)d_in[3];
    const float* wq   = (const float*)d_in[4];
    const float* wk   = (const float*)d_in[5];
    const float* wv   = (const float*)d_in[6];
    const float* wo   = (const float*)d_in[7];
    const float* qw   = (const float*)d_in[8];
    const float* kw   = (const float*)d_in[9];
    const float* sink = (const float*)d_in[10];
    float* out = (float*)d_out;

    char* ws = (char*)d_ws;
    size_t off = 0;
    auto alloc = [&](size_t bytes) {
        char* p = ws + off;
        off += (bytes + 255) & ~(size_t)255;
        return p;
    };
    u16*   xb    = (u16*)alloc((size_t)2048 * 2048 * 2);       // x bf16
    u16*   wqkvt = (u16*)alloc((size_t)3072 * 2048 * 2);       // [wq^T; wk^T; wv^T]
    u16*   wot   = (u16*)alloc((size_t)2048 * 2048 * 2);       // wo^T
    u16*   p0    = (u16*)alloc((size_t)2048 * 3072 * 2);       // GEMM1 partial z=0 (bf16)
    u16*   p1    = (u16*)alloc((size_t)2048 * 3072 * 2);       // GEMM1 partial z=1 (bf16)
    u16*   qnb   = (u16*)alloc((size_t)2048 * 2048 * 2);
    u16*   kfrag = (u16*)alloc((size_t)8 * 128 * 1024 * 2);
    u16*   vfrag = (u16*)alloc((size_t)8 * 64 * 2048 * 2);
    float* lbuf  = (float*)alloc((size_t)32 * 320 * 16 * 4);
    u16*   attnb = xb;        // xb dead after GEMM1
    u16*   obuf  = p0;        // p0+p1 (25.2 MB contiguous) dead after norm_rope/v_frag; obuf needs 21 MB
    u16*   o2p   = p0;        // obuf dead after merge_k; GEMM2 bf16 partials need 16.8 MB

    cast_bf16_k<<<2048, 256, 0, stream>>>(x, xb, 2048 * 2048 / 4);
    transpose_all_k<<<2560, 256, 0, stream>>>(wq, wk, wv, wo, wqkvt, wot);

    gemm_bt_dbuf_k<<<dim3(24, 16, 2), 256, 0, stream>>>(xb, wqkvt, p0, 2048, 3072, 2048);
    norm_rope_k<<<20480, 256, 0, stream>>>(p0, p1, cosb, sinb, qw, kw, qnb, kfrag);
    v_frag_k<<<dim3(32, 8), 256, 0, stream>>>(p0, p1, vfrag);

    attn_k<<<dim3(32, 160), 64, 0, stream>>>(qnb, kfrag, vfrag, obuf, lbuf);
    merge_k<<<2048, 256, 0, stream>>>(obuf, lbuf, sink, attnb);

    gemm_bt_dbuf_k<<<dim3(16, 16, 2), 256, 0, stream>>>(attnb, wot, o2p, 2048, 2048, 2048);
    sum2_f32_k<<<2048, 256, 0, stream>>>(o2p, o2p + (size_t)2048 * 2048, out, 2048 * 2048 / 8);
}

// Round 16
// 138.555 us; speedup vs baseline: 1.1445x; 1.0157x over previous
//
#include <hip/hip_runtime.h>

typedef unsigned short u16;
typedef __bf16 bf16;
typedef float f32x4 __attribute__((ext_vector_type(4)));
typedef bf16 bf16x8 __attribute__((ext_vector_type(8)));
typedef short s16x4 __attribute__((ext_vector_type(4)));
typedef u16 u16x4 __attribute__((ext_vector_type(4)));
typedef u16 u16x8 __attribute__((ext_vector_type(8)));

#define SEQ 2048
#define LOG2E 1.4426950408889634f

__device__ __forceinline__ u16 f2bf(float f) {
    return __builtin_bit_cast(u16, (bf16)f);
}
__device__ __forceinline__ float bf2f(u16 u) {
    unsigned int w = ((unsigned int)u) << 16;
    return __builtin_bit_cast(float, w);
}

// ---------------- fused prep: x cast (blocks 0..2047) + all 4 weight transposes ----------------
// blocks [2048,3072): wq  [3072,3328): wk  [3328,3584): wv  [3584,4608): wo
__global__ __launch_bounds__(256) void prep_k(const float* __restrict__ x,
                                              const float* __restrict__ wq,
                                              const float* __restrict__ wk,
                                              const float* __restrict__ wv,
                                              const float* __restrict__ wo,
                                              u16* __restrict__ xb,
                                              u16* __restrict__ wqkvt,
                                              u16* __restrict__ wot) {
    __shared__ float t[64][65];
    int b = blockIdx.x;
    if (b < 2048) {
        int i = b * 256 + threadIdx.x;   // n4 = 2048*2048/4 = 1048576; stride covers in 2 iters
#pragma unroll
        for (int it = 0; it < 2; ++it, i += 524288) {
            float4 v = reinterpret_cast<const float4*>(x)[i];
            u16x4 o;
            o[0] = f2bf(v.x); o[1] = f2bf(v.y); o[2] = f2bf(v.z); o[3] = f2bf(v.w);
            reinterpret_cast<u16x4*>(xb)[i] = o;
        }
        return;
    }
    b -= 2048;
    const float* src;
    u16* dst;
    int C, bx, by;
    if (b < 1024)      { src = wq; dst = wqkvt;                          C = 2048; bx = b & 31; by = b >> 5; }
    else if (b < 1280) { b -= 1024; src = wk; dst = wqkvt + (size_t)2048 * 2048; C = 512; bx = b & 7; by = b >> 3; }
    else if (b < 1536) { b -= 1280; src = wv; dst = wqkvt + (size_t)2560 * 2048; C = 512; bx = b & 7; by = b >> 3; }
    else               { b -= 1536; src = wo; dst = wot;                 C = 2048; bx = b & 31; by = b >> 5; }
    int c0 = bx * 64, r0 = by * 64;
    int tx = threadIdx.x & 63, ty = threadIdx.x >> 6;
#pragma unroll
    for (int i = 0; i < 16; ++i) {
        int r = ty + i * 4;
        t[r][tx] = src[(size_t)(r0 + r) * C + c0 + tx];
    }
    __syncthreads();
#pragma unroll
    for (int i = 0; i < 16; ++i) {
        int c = ty + i * 4;
        dst[(size_t)(c0 + c) * 2048 + r0 + tx] = f2bf(t[tx][c]);
    }
}

// ---------------- GEMM partial: Cp[z][M,N](bf16) = A[M,kz] @ Bt[N,kz]^T ----------------
// 128x128 tile, BK=32, split-K=2, double-buffered LDS with prefetch,
// + bijective XCD swizzle (T1, validated R15: FETCH 41->~25MB, both GEMMs < 38.5us).
// XOR-swizzled LDS slots (pre-swizzled gload_lds source + swizzled ds_read; rule #21).
__global__ __launch_bounds__(256) void gemm_bt_dbuf_k(const u16* __restrict__ A,
                                                      const u16* __restrict__ Bt,
                                                      u16* __restrict__ Cp,
                                                      int M, int N, int K) {
    __shared__ __align__(16) u16 As[2][128 * 32];
    __shared__ __align__(16) u16 Bs[2][128 * 32];
    int tid = threadIdx.x;
    int wave = tid >> 6, lane = tid & 63;

    // XCD-aware bijective work remap
    unsigned nx = gridDim.x, ny = gridDim.y;
    unsigned nwg = nx * ny * gridDim.z;
    unsigned id = blockIdx.x + nx * (blockIdx.y + ny * blockIdx.z);
    unsigned qq = nwg >> 3;
    unsigned swz = (id & 7) * qq + (id >> 3);
    unsigned bxw = swz % nx;
    unsigned rem = swz / nx;
    unsigned byw = rem % ny;
    unsigned bzw = rem / ny;
    int bm = byw * 128, bn = bxw * 128;
    int z = bzw;

    int kslice = K / gridDim.z;
    int kt0 = z * kslice, ktend = kt0 + kslice;
    int wm = (wave >> 1) * 64, wn = (wave & 1) * 64;
    int g = lane >> 4, cidx = lane & 15;
    f32x4 acc[4][4] = {};

    int srow = lane >> 2;
    int skol = ((lane & 3) ^ ((srow >> 1) & 3)) * 8;
    int sl8 = (g ^ ((cidx >> 1) & 3)) * 8;

#define STAGE(buf, kt)                                                                \
    {                                                                                 \
        _Pragma("unroll")                                                             \
        for (int j = 0; j < 2; ++j) {                                                 \
            const u16* gpa = A + (size_t)(bm + (wave * 2 + j) * 16 + srow) * K + (kt) + skol; \
            __builtin_amdgcn_global_load_lds(                                         \
                (__attribute__((address_space(1))) void*)gpa,                         \
                (__attribute__((address_space(3))) void*)&As[buf][(wave * 2 + j) * 512], \
                16, 0, 0);                                                            \
        }                                                                             \
        _Pragma("unroll")                                                             \
        for (int j = 0; j < 2; ++j) {                                                 \
            const u16* gpb = Bt + (size_t)(bn + (wave * 2 + j) * 16 + srow) * K + (kt) + skol; \
            __builtin_amdgcn_global_load_lds(                                         \
                (__attribute__((address_space(1))) void*)gpb,                         \
                (__attribute__((address_space(3))) void*)&Bs[buf][(wave * 2 + j) * 512], \
                16, 0, 0);                                                            \
        }                                                                             \
    }

    STAGE(0, kt0);
    asm volatile("s_waitcnt vmcnt(0)" ::: "memory");
    __syncthreads();

    int cur = 0;
#pragma unroll 1
    for (int kt = kt0; kt < ktend; kt += 32) {
        if (kt + 32 < ktend) STAGE(cur ^ 1, kt + 32);

        bf16x8 af[4], bfr[4];
#pragma unroll
        for (int mi = 0; mi < 4; ++mi)
            af[mi] = *reinterpret_cast<const bf16x8*>(&As[cur][(wm + mi * 16 + cidx) * 32 + sl8]);
#pragma unroll
        for (int ni = 0; ni < 4; ++ni)
            bfr[ni] = *reinterpret_cast<const bf16x8*>(&Bs[cur][(wn + ni * 16 + cidx) * 32 + sl8]);
#pragma unroll
        for (int mi = 0; mi < 4; ++mi)
#pragma unroll
            for (int ni = 0; ni < 4; ++ni)
                acc[mi][ni] = __builtin_amdgcn_mfma_f32_16x16x32_bf16(af[mi], bfr[ni], acc[mi][ni], 0, 0, 0);

        asm volatile("s_waitcnt vmcnt(0)" ::: "memory");
        __syncthreads();
        cur ^= 1;
    }
#undef STAGE

    u16* cbase = Cp + (size_t)z * M * N;
#pragma unroll
    for (int mi = 0; mi < 4; ++mi) {
#pragma unroll
        for (int r = 0; r < 4; ++r) {
            int row = bm + wm + mi * 16 + g * 4 + r;
            u16* cp = cbase + (size_t)row * N + bn + wn + cidx;
#pragma unroll
            for (int ni = 0; ni < 4; ++ni)
                cp[ni * 16] = f2bf(acc[mi][ni][r]);
        }
    }
}

// ---------------- sum two bf16 partials -> f32 ----------------
__global__ __launch_bounds__(256) void sum2_f32_k(const u16* __restrict__ a,
                                                  const u16* __restrict__ b,
                                                  float* __restrict__ out, int n8) {
    int i = blockIdx.x * 256 + threadIdx.x;
    if (i >= n8) return;
    u16x8 va = reinterpret_cast<const u16x8*>(a)[i];
    u16x8 vb = reinterpret_cast<const u16x8*>(b)[i];
    f32x4 lo, hi;
#pragma unroll
    for (int j = 0; j < 4; ++j) {
        lo[j] = bf2f(va[j]) + bf2f(vb[j]);
        hi[j] = bf2f(va[4 + j]) + bf2f(vb[4 + j]);
    }
    reinterpret_cast<f32x4*>(out)[i * 2] = lo;
    reinterpret_cast<f32x4*>(out)[i * 2 + 1] = hi;
}

// ---------------- fused post-GEMM1: RMSNorm+RoPE (blocks 0..20479) + V-frag ----------------
// Q: pre-scaled by 0.125*log2(e); K in permuted MFMA A-frag order (see R7 comment);
// V blocks [20480, 20736): vfrag[kvh][kb32][dt][lane][i] = V[kb32*32+g*8+i][dt*16+cc].
__global__ __launch_bounds__(256) void postgemm_k(const u16* __restrict__ p0,
                                                  const u16* __restrict__ p1,
                                                  const float* __restrict__ cosb,
                                                  const float* __restrict__ sinb,
                                                  const float* __restrict__ qw,
                                                  const float* __restrict__ kw,
                                                  u16* __restrict__ qn,
                                                  u16* __restrict__ kfrag,
                                                  u16* __restrict__ vfrag) {
    __shared__ float t[64][65];
    int b = blockIdx.x;
    if (b < 20480) {
        int idx = b * 4 + (threadIdx.x >> 6);
        int lane = threadIdx.x & 63;
        int s = idx / 40, hh = idx - s * 40;
        size_t off = (hh < 32) ? ((size_t)s * 3072 + hh * 64 + lane)
                               : ((size_t)s * 3072 + 2048 + (hh - 32) * 64 + lane);
        float val = bf2f(p0[off]) + bf2f(p1[off]);
        float ss = val * val;
#pragma unroll
        for (int mm = 32; mm; mm >>= 1) ss += __shfl_xor(ss, mm);
        float w = (hh < 32) ? qw[lane] : kw[lane];
        float xn = val * rsqrtf(ss * (1.f / 64.f) + 1e-6f) * w;
        float part = __shfl_xor(xn, 32);
        float rot = (lane < 32) ? -part : part;
        float o = xn * cosb[s * 64 + lane] + rot * sinb[s * 64 + lane];
        if (hh < 32) {
            qn[(size_t)s * 2048 + hh * 64 + lane] = f2bf(o * (0.125f * LOG2E));
        } else {
            int h8 = hh - 32;
            int k32 = s & 31;
            int p32 = ((k32 >> 2) & 1) * 16 + ((k32 >> 3) << 2) + (k32 & 3);
            int p = (s & ~31) + p32;
            kfrag[(((size_t)h8 * 128 + (p >> 4)) << 10) + (lane >> 3) * 128 + (p & 15) * 8 + (lane & 7)] = f2bf(o);
        }
        return;
    }
    int vb = b - 20480;            // 0..255
    int s0 = (vb & 31) * 64, h = vb >> 5;
    int tx = threadIdx.x & 63, ty = threadIdx.x >> 6;
#pragma unroll
    for (int i = 0; i < 16; ++i) {
        int r = ty + i * 4;
        size_t off = (size_t)(s0 + r) * 3072 + 2560 + h * 64 + tx;
        t[r][tx] = bf2f(p0[off]) + bf2f(p1[off]);
    }
    __syncthreads();
    int dt = threadIdx.x >> 6, g = (threadIdx.x >> 4) & 3, cc = threadIdx.x & 15;
#pragma unroll
    for (int kb = 0; kb < 2; ++kb) {
        u16x8 o;
#pragma unroll
        for (int i = 0; i < 8; ++i) o[i] = f2bf(t[kb * 32 + g * 8 + i][dt * 16 + cc]);
        *reinterpret_cast<u16x8*>(
            &vfrag[((size_t)h * 64 + (s0 >> 5) + kb) * 2048 + dt * 512 + (size_t)(threadIdx.x & 63) * 8]) = o;
    }
}

// ---------------- Flash attention: 32 q-rows/wave, register-lifetime-ordered phases ----------------
// R16 reorder for 4 waves/SIMD: loadK -> QK_A -> softmaxA->pbA(4reg, stA dies) ->
// QK_B -> loadV (K dead before V arrives) -> softmaxB -> PV_A -> PV_B.
// Peak live ~115-120 regs vs R12's ~145 (K,V,stA,stB co-live) -> (64,4) cap 128 fits.
// Cost: V latency covered only by softmax_B; won by +33% TLP (kernel is latency-bound).
// NOTE: VGPR caps: (256,8)->32 regs spilled 1.3GB (R4); interleaved dual-stream ~190
// regs spilled (R9). Tripwire: attn FETCH/WRITE >> 30MB means spill -> revert to (64,3).
__global__ __launch_bounds__(64, 4) void attn_k(const u16* __restrict__ qn,
                                                const u16* __restrict__ kfrag,
                                                const u16* __restrict__ vfrag,
                                                u16* __restrict__ obuf,
                                                float* __restrict__ lbuf) {
    int h = blockIdx.x;
    int kvh = h >> 2;
    int lane = threadIdx.x;
    int item = 159 - blockIdx.y;   // reversed: 4-window pairs (most iters) first
    int t, w;
    if (item < 16)      { t = item;                    w = 0; }
    else if (item < 48) { t = 16 + ((item - 16) >> 1); w = (item - 16) & 1; }
    else if (item < 96) { int r = item - 48; int q = r / 3; t = 32 + q; w = r - 3 * q; }
    else                { t = 48 + ((item - 96) >> 2); w = (item - 96) & 3; }

    int qA0 = t * 32;
    int qB0 = qA0 + 16;
    int kv0 = w * 512;
    int nkA = qA0 + 16, nkB = qB0 + 16;
    int kvend = (kv0 + 512 < nkB) ? (kv0 + 512) : nkB;

    int g = lane >> 4, cc = lane & 15;
    int qrowA = qA0 + cc, qrowB = qB0 + cc;

    const size_t qoffA = (size_t)qrowA * 2048 + h * 64;
    const size_t qoffB = (size_t)qrowB * 2048 + h * 64;
    bf16x8 qa0 = *reinterpret_cast<const bf16x8*>(&qn[qoffA + g * 8]);
    bf16x8 qa1 = *reinterpret_cast<const bf16x8*>(&qn[qoffA + 32 + g * 8]);
    bf16x8 qb0 = *reinterpret_cast<const bf16x8*>(&qn[qoffB + g * 8]);
    bf16x8 qb1 = *reinterpret_cast<const bf16x8*>(&qn[qoffB + 32 + g * 8]);

    float lA = 0.f, lB = 0.f;
    f32x4 oA[4] = {}, oB[4] = {};

    const u16* kbase = kfrag + (((size_t)kvh * 128) << 10) + lane * 8;
    const u16* vbase = vfrag + (size_t)kvh * 64 * 2048 + lane * 8;

#pragma unroll 1
    for (; kv0 < kvend; kv0 += 64) {
        bool doA = kv0 < nkA;
        u16x8 pbA[2], pbB[2];

        // ---- K phase: load K, both QK^T + softmaxes; K dies before V loads ----
        {
            bf16x8 kf0[4], kf1[4];
#pragma unroll
            for (int sub = 0; sub < 4; ++sub) {
                const u16* kp = kbase + (size_t)((kv0 >> 4) + sub) * 1024;
                kf0[sub] = *reinterpret_cast<const bf16x8*>(kp);
                kf1[sub] = *reinterpret_cast<const bf16x8*>(kp + 512);
            }
            if (doA) {
                f32x4 st[4];
                __builtin_amdgcn_s_setprio(1);
#pragma unroll
                for (int sub = 0; sub < 4; ++sub) {
                    st[sub] = __builtin_amdgcn_mfma_f32_16x16x32_bf16(kf0[sub], qa0, (f32x4){0.f, 0.f, 0.f, 0.f}, 0, 0, 0);
                    st[sub] = __builtin_amdgcn_mfma_f32_16x16x32_bf16(kf1[sub], qa1, st[sub], 0, 0, 0);
                }
                __builtin_amdgcn_s_setprio(0);
                if (kv0 + 64 > qA0) {
#pragma unroll
                    for (int sub = 0; sub < 4; ++sub)
#pragma unroll
                        for (int r = 0; r < 4; ++r) {
                            int key = kv0 + (sub >> 1) * 32 + g * 8 + (sub & 1) * 4 + r;
                            if (key > qrowA) st[sub][r] = -1e30f;
                        }
                }
                float rs = 0.f;
#pragma unroll
                for (int sub = 0; sub < 4; ++sub)
#pragma unroll
                    for (int r = 0; r < 4; ++r) {
                        float e = __builtin_amdgcn_exp2f(st[sub][r]);
                        rs += e;
                        pbA[sub >> 1][(sub & 1) * 4 + r] = f2bf(e);
                    }
                lA += rs;
            }
            f32x4 st[4];
            __builtin_amdgcn_s_setprio(1);
#pragma unroll
            for (int sub = 0; sub < 4; ++sub) {
                st[sub] = __builtin_amdgcn_mfma_f32_16x16x32_bf16(kf0[sub], qb0, (f32x4){0.f, 0.f, 0.f, 0.f}, 0, 0, 0);
                st[sub] = __builtin_amdgcn_mfma_f32_16x16x32_bf16(kf1[sub], qb1, st[sub], 0, 0, 0);
            }
            __builtin_amdgcn_s_setprio(0);
            if (kv0 + 64 > qB0) {
#pragma unroll
                for (int sub = 0; sub < 4; ++sub)
#pragma unroll
                    for (int r = 0; r < 4; ++r) {
                        int key = kv0 + (sub >> 1) * 32 + g * 8 + (sub & 1) * 4 + r;
                        if (key > qrowB) st[sub][r] = -1e30f;
                    }
            }
            float rs = 0.f;
#pragma unroll
            for (int sub = 0; sub < 4; ++sub)
#pragma unroll
                for (int r = 0; r < 4; ++r) {
                    float e = __builtin_amdgcn_exp2f(st[sub][r]);
                    rs += e;
                    pbB[sub >> 1][(sub & 1) * 4 + r] = f2bf(e);
                }
            lB += rs;
        }

        // ---- V phase: load V (K regs free), PV for both streams ----
        bf16x8 vv[2][4];
#pragma unroll
        for (int sp = 0; sp < 2; ++sp)
#pragma unroll
            for (int dt = 0; dt < 4; ++dt)
                vv[sp][dt] = *reinterpret_cast<const bf16x8*>(
                    vbase + (size_t)((kv0 >> 5) + sp) * 2048 + dt * 512);

        __builtin_amdgcn_s_setprio(1);
#pragma unroll
        for (int sp = 0; sp < 2; ++sp) {
            bf16x8 pa = __builtin_bit_cast(bf16x8, pbA[sp]);
            bf16x8 pb = __builtin_bit_cast(bf16x8, pbB[sp]);
#pragma unroll
            for (int dt = 0; dt < 4; ++dt) {
                if (doA) oA[dt] = __builtin_amdgcn_mfma_f32_16x16x32_bf16(vv[sp][dt], pa, oA[dt], 0, 0, 0);
                oB[dt] = __builtin_amdgcn_mfma_f32_16x16x32_bf16(vv[sp][dt], pb, oB[dt], 0, 0, 0);
            }
        }
        __builtin_amdgcn_s_setprio(0);
    }

    // private-slot partial writes; slot = (h*160+item)*2+half
    lA += __shfl_xor(lA, 16);
    lA += __shfl_xor(lA, 32);
    lB += __shfl_xor(lB, 16);
    lB += __shfl_xor(lB, 32);
    size_t slotA = ((size_t)h * 160 + item) * 2;
    if (lane < 16) {
        lbuf[slotA * 16 + cc] = lA;
        lbuf[(slotA + 1) * 16 + cc] = lB;
    }
    u16* spA = obuf + slotA * 1024;
    u16* spB = obuf + (slotA + 1) * 1024;
#pragma unroll
    for (int dt = 0; dt < 4; ++dt) {
        u16x4 ovA, ovB;
#pragma unroll
        for (int r = 0; r < 4; ++r) {
            ovA[r] = f2bf(oA[dt][r]);
            ovB[r] = f2bf(oB[dt][r]);
        }
        *reinterpret_cast<u16x4*>(&spA[cc * 64 + dt * 16 + g * 4]) = ovA;
        *reinterpret_cast<u16x4*>(&spB[cc * 64 + dt * 16 + g * 4]) = ovB;
    }
}

// ---------------- merge: attn_bf16 = sum(o_w) / (sum(l_w) + 2^(sink*log2e)) ----------------
__global__ __launch_bounds__(256) void merge_k(const u16* __restrict__ obuf,
                                               const float* __restrict__ lbuf,
                                               const float* __restrict__ sink,
                                               u16* __restrict__ attnb) {
    int row = blockIdx.x;
    int c = row >> 4, cc = row & 15;
    int t2 = c >> 1, half = c & 1;
    int nw = (t2 >> 4) + 1;
    int jb = (t2 < 16) ? t2
           : (t2 < 32) ? 16 + ((t2 - 16) << 1)
           : (t2 < 48) ? 48 + 3 * (t2 - 32)
                       : 96 + ((t2 - 48) << 2);
    int t = threadIdx.x;
    int h = t >> 3, col0 = (t & 7) * 8;

    float acc[8] = {};
    float lsum = __builtin_amdgcn_exp2f(sink[h] * LOG2E);
#pragma unroll 1
    for (int w = 0; w < nw; ++w) {
        size_t slot = ((size_t)h * 160 + jb + w) * 2 + half;
        lsum += lbuf[slot * 16 + cc];
        u16x8 v = *reinterpret_cast<const u16x8*>(&obuf[slot * 1024 + cc * 64 + col0]);
#pragma unroll
        for (int i = 0; i < 8; ++i) acc[i] += bf2f(v[i]);
    }
    float inv = 1.f / lsum;
    u16x8 ob;
#pragma unroll
    for (int i = 0; i < 8; ++i) ob[i] = f2bf(acc[i] * inv);
    *reinterpret_cast<u16x8*>(&attnb[(size_t)row * 2048 + h * 64 + col0]) = ob;
}

extern "C" void kernel_launch(void* const* d_in, const int* in_sizes, int n_in,
                              void* d_out, int out_size, void* d_ws, size_t ws_size,
                              hipStream_t stream) {
    const float* x    = (const float*)d_in[0];
    const float* cosb = (const float*)d_in[2];
    const float* sinb = (const float*)d_in[3];
    const float* wq   = (const float*)d_in[4];
    const float* wk   = (const float*)d_in[5];
    const float* wv   = (const float*)d_in[6];
    const float* wo   = (const float*)d_in[7];
    const float* qw   = (const float*)d_in[8];
    const float* kw   = (const float*)d_in[9];
    const float* sink = (const float*)d_in[10];
    float* out = (float*)d_out;

    char* ws = (char*)d_ws;
    size_t off = 0;
    auto alloc = [&](size_t bytes) {
        char* p = ws + off;
        off += (bytes + 255) & ~(size_t)255;
        return p;
    };
    u16*   xb    = (u16*)alloc((size_t)2048 * 2048 * 2);       // x bf16
    u16*   wqkvt = (u16*)alloc((size_t)3072 * 2048 * 2);       // [wq^T; wk^T; wv^T]
    u16*   wot   = (u16*)alloc((size_t)2048 * 2048 * 2);       // wo^T
    u16*   p0    = (u16*)alloc((size_t)2048 * 3072 * 2);       // GEMM1 partial z=0 (bf16)
    u16*   p1    = (u16*)alloc((size_t)2048 * 3072 * 2);       // GEMM1 partial z=1 (bf16)
    u16*   qnb   = (u16*)alloc((size_t)2048 * 2048 * 2);
    u16*   kfrag = (u16*)alloc((size_t)8 * 128 * 1024 * 2);
    u16*   vfrag = (u16*)alloc((size_t)8 * 64 * 2048 * 2);
    float* lbuf  = (float*)alloc((size_t)32 * 320 * 16 * 4);
    u16*   attnb = xb;        // xb dead after GEMM1
    u16*   obuf  = p0;        // p0+p1 dead after postgemm; obuf needs 21 MB
    u16*   o2p   = p0;        // obuf dead after merge_k; GEMM2 bf16 partials need 16.8 MB

    prep_k<<<4608, 256, 0, stream>>>(x, wq, wk, wv, wo, xb, wqkvt, wot);

    gemm_bt_dbuf_k<<<dim3(24, 16, 2), 256, 0, stream>>>(xb, wqkvt, p0, 2048, 3072, 2048);
    postgemm_k<<<20736, 256, 0, stream>>>(p0, p1, cosb, sinb, qw, kw, qnb, kfrag, vfrag);

    attn_k<<<dim3(32, 160), 64, 0, stream>>>(qnb, kfrag, vfrag, obuf, lbuf);
    merge_k<<<2048, 256, 0, stream>>>(obuf, lbuf, sink, attnb);

    gemm_bt_dbuf_k<<<dim3(16, 16, 2), 256, 0, stream>>>(attnb, wot, o2p, 2048, 2048, 2048);
    sum2_f32_k<<<2048, 256, 0, stream>>>(o2p, o2p + (size_t)2048 * 2048, out, 2048 * 2048 / 8);
}

// Round 17
// 137.247 us; speedup vs baseline: 1.1554x; 1.0095x over previous
//
#include <hip/hip_runtime.h>

typedef unsigned short u16;
typedef __bf16 bf16;
typedef float f32x4 __attribute__((ext_vector_type(4)));
typedef bf16 bf16x8 __attribute__((ext_vector_type(8)));
typedef short s16x4 __attribute__((ext_vector_type(4)));
typedef u16 u16x4 __attribute__((ext_vector_type(4)));
typedef u16 u16x8 __attribute__((ext_vector_type(8)));

#define SEQ 2048
#define LOG2E 1.4426950408889634f

__device__ __forceinline__ u16 f2bf(float f) {
    return __builtin_bit_cast(u16, (bf16)f);
}
__device__ __forceinline__ float bf2f(u16 u) {
    unsigned int w = ((unsigned int)u) << 16;
    return __builtin_bit_cast(float, w);
}

// ---------------- fused prep: x cast (blocks 0..2047) + all 4 weight transposes ----------------
__global__ __launch_bounds__(256) void prep_k(const float* __restrict__ x,
                                              const float* __restrict__ wq,
                                              const float* __restrict__ wk,
                                              const float* __restrict__ wv,
                                              const float* __restrict__ wo,
                                              u16* __restrict__ xb,
                                              u16* __restrict__ wqkvt,
                                              u16* __restrict__ wot) {
    __shared__ float t[64][65];
    int b = blockIdx.x;
    if (b < 2048) {
        int i = b * 256 + threadIdx.x;
#pragma unroll
        for (int it = 0; it < 2; ++it, i += 524288) {
            float4 v = reinterpret_cast<const float4*>(x)[i];
            u16x4 o;
            o[0] = f2bf(v.x); o[1] = f2bf(v.y); o[2] = f2bf(v.z); o[3] = f2bf(v.w);
            reinterpret_cast<u16x4*>(xb)[i] = o;
        }
        return;
    }
    b -= 2048;
    const float* src;
    u16* dst;
    int C, bx, by;
    if (b < 1024)      { src = wq; dst = wqkvt;                          C = 2048; bx = b & 31; by = b >> 5; }
    else if (b < 1280) { b -= 1024; src = wk; dst = wqkvt + (size_t)2048 * 2048; C = 512; bx = b & 7; by = b >> 3; }
    else if (b < 1536) { b -= 1280; src = wv; dst = wqkvt + (size_t)2560 * 2048; C = 512; bx = b & 7; by = b >> 3; }
    else               { b -= 1536; src = wo; dst = wot;                 C = 2048; bx = b & 31; by = b >> 5; }
    int c0 = bx * 64, r0 = by * 64;
    int tx = threadIdx.x & 63, ty = threadIdx.x >> 6;
#pragma unroll
    for (int i = 0; i < 16; ++i) {
        int r = ty + i * 4;
        t[r][tx] = src[(size_t)(r0 + r) * C + c0 + tx];
    }
    __syncthreads();
#pragma unroll
    for (int i = 0; i < 16; ++i) {
        int c = ty + i * 4;
        dst[(size_t)(c0 + c) * 2048 + r0 + tx] = f2bf(t[tx][c]);
    }
}

// ---------------- GEMM partial: Cp[z][M,N](bf16) = A[M,kz] @ Bt[N,kz]^T ----------------
// R17: 128x128 tile, BK=32, split-K=2, but EIGHT thin waves (512 thr), each owning
// 32x64 (acc 2x4 = 32 AGPR; ~100 unified regs -> 5 waves/SIMD cap vs 3 for the old
// 4-wave/4x4 at 132 regs). Same grid -> 3 blocks/CU x 2 waves/SIMD = ~5-6 resident
// waves/SIMD to hide the ~3000cyc/iter latency (R12-R16: not vmcnt-depth, not block
// count, not L2 locality). dbuf + XOR LDS swizzle + bijective XCD swizzle retained.
__global__ __launch_bounds__(512) void gemm_bt_dbuf_k(const u16* __restrict__ A,
                                                      const u16* __restrict__ Bt,
                                                      u16* __restrict__ Cp,
                                                      int M, int N, int K) {
    __shared__ __align__(16) u16 As[2][128 * 32];
    __shared__ __align__(16) u16 Bs[2][128 * 32];
    int tid = threadIdx.x;
    int wave = tid >> 6, lane = tid & 63;

    // XCD-aware bijective work remap
    unsigned nx = gridDim.x, ny = gridDim.y;
    unsigned nwg = nx * ny * gridDim.z;
    unsigned id = blockIdx.x + nx * (blockIdx.y + ny * blockIdx.z);
    unsigned qq = nwg >> 3;
    unsigned swz = (id & 7) * qq + (id >> 3);
    unsigned bxw = swz % nx;
    unsigned rem = swz / nx;
    unsigned byw = rem % ny;
    unsigned bzw = rem / ny;
    int bm = byw * 128, bn = bxw * 128;
    int z = bzw;

    int kslice = K / gridDim.z;
    int kt0 = z * kslice, ktend = kt0 + kslice;
    int wm = (wave >> 1) * 32, wn = (wave & 1) * 64;
    int g = lane >> 4, cidx = lane & 15;
    f32x4 acc[2][4] = {};

    int srow = lane >> 2;
    int skol = ((lane & 3) ^ ((srow >> 1) & 3)) * 8;
    int sl8 = (g ^ ((cidx >> 1) & 3)) * 8;

    // each wave stages ONE 16-row chunk of A and one of B (8 waves x 16 = 128 rows)
#define STAGE(buf, kt)                                                                \
    {                                                                                 \
        const u16* gpa = A + (size_t)(bm + wave * 16 + srow) * K + (kt) + skol;       \
        __builtin_amdgcn_global_load_lds(                                             \
            (__attribute__((address_space(1))) void*)gpa,                             \
            (__attribute__((address_space(3))) void*)&As[buf][wave * 512],            \
            16, 0, 0);                                                                \
        const u16* gpb = Bt + (size_t)(bn + wave * 16 + srow) * K + (kt) + skol;      \
        __builtin_amdgcn_global_load_lds(                                             \
            (__attribute__((address_space(1))) void*)gpb,                             \
            (__attribute__((address_space(3))) void*)&Bs[buf][wave * 512],            \
            16, 0, 0);                                                                \
    }

    STAGE(0, kt0);
    asm volatile("s_waitcnt vmcnt(0)" ::: "memory");
    __syncthreads();

    int cur = 0;
#pragma unroll 1
    for (int kt = kt0; kt < ktend; kt += 32) {
        if (kt + 32 < ktend) STAGE(cur ^ 1, kt + 32);

        bf16x8 af[2], bfr[4];
#pragma unroll
        for (int mi = 0; mi < 2; ++mi)
            af[mi] = *reinterpret_cast<const bf16x8*>(&As[cur][(wm + mi * 16 + cidx) * 32 + sl8]);
#pragma unroll
        for (int ni = 0; ni < 4; ++ni)
            bfr[ni] = *reinterpret_cast<const bf16x8*>(&Bs[cur][(wn + ni * 16 + cidx) * 32 + sl8]);
#pragma unroll
        for (int mi = 0; mi < 2; ++mi)
#pragma unroll
            for (int ni = 0; ni < 4; ++ni)
                acc[mi][ni] = __builtin_amdgcn_mfma_f32_16x16x32_bf16(af[mi], bfr[ni], acc[mi][ni], 0, 0, 0);

        asm volatile("s_waitcnt vmcnt(0)" ::: "memory");
        __syncthreads();
        cur ^= 1;
    }
#undef STAGE

    u16* cbase = Cp + (size_t)z * M * N;
#pragma unroll
    for (int mi = 0; mi < 2; ++mi) {
#pragma unroll
        for (int r = 0; r < 4; ++r) {
            int row = bm + wm + mi * 16 + g * 4 + r;
            u16* cp = cbase + (size_t)row * N + bn + wn + cidx;
#pragma unroll
            for (int ni = 0; ni < 4; ++ni)
                cp[ni * 16] = f2bf(acc[mi][ni][r]);
        }
    }
}

// ---------------- sum two bf16 partials -> f32 ----------------
__global__ __launch_bounds__(256) void sum2_f32_k(const u16* __restrict__ a,
                                                  const u16* __restrict__ b,
                                                  float* __restrict__ out, int n8) {
    int i = blockIdx.x * 256 + threadIdx.x;
    if (i >= n8) return;
    u16x8 va = reinterpret_cast<const u16x8*>(a)[i];
    u16x8 vb = reinterpret_cast<const u16x8*>(b)[i];
    f32x4 lo, hi;
#pragma unroll
    for (int j = 0; j < 4; ++j) {
        lo[j] = bf2f(va[j]) + bf2f(vb[j]);
        hi[j] = bf2f(va[4 + j]) + bf2f(vb[4 + j]);
    }
    reinterpret_cast<f32x4*>(out)[i * 2] = lo;
    reinterpret_cast<f32x4*>(out)[i * 2 + 1] = hi;
}

// ---------------- fused post-GEMM1: RMSNorm+RoPE (blocks 0..20479) + V-frag ----------------
__global__ __launch_bounds__(256) void postgemm_k(const u16* __restrict__ p0,
                                                  const u16* __restrict__ p1,
                                                  const float* __restrict__ cosb,
                                                  const float* __restrict__ sinb,
                                                  const float* __restrict__ qw,
                                                  const float* __restrict__ kw,
                                                  u16* __restrict__ qn,
                                                  u16* __restrict__ kfrag,
                                                  u16* __restrict__ vfrag) {
    __shared__ float t[64][65];
    int b = blockIdx.x;
    if (b < 20480) {
        int idx = b * 4 + (threadIdx.x >> 6);
        int lane = threadIdx.x & 63;
        int s = idx / 40, hh = idx - s * 40;
        size_t off = (hh < 32) ? ((size_t)s * 3072 + hh * 64 + lane)
                               : ((size_t)s * 3072 + 2048 + (hh - 32) * 64 + lane);
        float val = bf2f(p0[off]) + bf2f(p1[off]);
        float ss = val * val;
#pragma unroll
        for (int mm = 32; mm; mm >>= 1) ss += __shfl_xor(ss, mm);
        float w = (hh < 32) ? qw[lane] : kw[lane];
        float xn = val * rsqrtf(ss * (1.f / 64.f) + 1e-6f) * w;
        float part = __shfl_xor(xn, 32);
        float rot = (lane < 32) ? -part : part;
        float o = xn * cosb[s * 64 + lane] + rot * sinb[s * 64 + lane];
        if (hh < 32) {
            qn[(size_t)s * 2048 + hh * 64 + lane] = f2bf(o * (0.125f * LOG2E));
        } else {
            int h8 = hh - 32;
            int k32 = s & 31;
            int p32 = ((k32 >> 2) & 1) * 16 + ((k32 >> 3) << 2) + (k32 & 3);
            int p = (s & ~31) + p32;
            kfrag[(((size_t)h8 * 128 + (p >> 4)) << 10) + (lane >> 3) * 128 + (p & 15) * 8 + (lane & 7)] = f2bf(o);
        }
        return;
    }
    int vb = b - 20480;
    int s0 = (vb & 31) * 64, h = vb >> 5;
    int tx = threadIdx.x & 63, ty = threadIdx.x >> 6;
#pragma unroll
    for (int i = 0; i < 16; ++i) {
        int r = ty + i * 4;
        size_t off = (size_t)(s0 + r) * 3072 + 2560 + h * 64 + tx;
        t[r][tx] = bf2f(p0[off]) + bf2f(p1[off]);
    }
    __syncthreads();
    int dt = threadIdx.x >> 6, g = (threadIdx.x >> 4) & 3, cc = threadIdx.x & 15;
#pragma unroll
    for (int kb = 0; kb < 2; ++kb) {
        u16x8 o;
#pragma unroll
        for (int i = 0; i < 8; ++i) o[i] = f2bf(t[kb * 32 + g * 8 + i][dt * 16 + cc]);
        *reinterpret_cast<u16x8*>(
            &vfrag[((size_t)h * 64 + (s0 >> 5) + kb) * 2048 + dt * 512 + (size_t)(threadIdx.x & 63) * 8]) = o;
    }
}

// ---------------- Flash attention: 32 q-rows/wave, register-lifetime-ordered phases ----------------
// (R16 structure, unchanged this round)
__global__ __launch_bounds__(64, 4) void attn_k(const u16* __restrict__ qn,
                                                const u16* __restrict__ kfrag,
                                                const u16* __restrict__ vfrag,
                                                u16* __restrict__ obuf,
                                                float* __restrict__ lbuf) {
    int h = blockIdx.x;
    int kvh = h >> 2;
    int lane = threadIdx.x;
    int item = 159 - blockIdx.y;
    int t, w;
    if (item < 16)      { t = item;                    w = 0; }
    else if (item < 48) { t = 16 + ((item - 16) >> 1); w = (item - 16) & 1; }
    else if (item < 96) { int r = item - 48; int q = r / 3; t = 32 + q; w = r - 3 * q; }
    else                { t = 48 + ((item - 96) >> 2); w = (item - 96) & 3; }

    int qA0 = t * 32;
    int qB0 = qA0 + 16;
    int kv0 = w * 512;
    int nkA = qA0 + 16, nkB = qB0 + 16;
    int kvend = (kv0 + 512 < nkB) ? (kv0 + 512) : nkB;

    int g = lane >> 4, cc = lane & 15;
    int qrowA = qA0 + cc, qrowB = qB0 + cc;

    const size_t qoffA = (size_t)qrowA * 2048 + h * 64;
    const size_t qoffB = (size_t)qrowB * 2048 + h * 64;
    bf16x8 qa0 = *reinterpret_cast<const bf16x8*>(&qn[qoffA + g * 8]);
    bf16x8 qa1 = *reinterpret_cast<const bf16x8*>(&qn[qoffA + 32 + g * 8]);
    bf16x8 qb0 = *reinterpret_cast<const bf16x8*>(&qn[qoffB + g * 8]);
    bf16x8 qb1 = *reinterpret_cast<const bf16x8*>(&qn[qoffB + 32 + g * 8]);

    float lA = 0.f, lB = 0.f;
    f32x4 oA[4] = {}, oB[4] = {};

    const u16* kbase = kfrag + (((size_t)kvh * 128) << 10) + lane * 8;
    const u16* vbase = vfrag + (size_t)kvh * 64 * 2048 + lane * 8;

#pragma unroll 1
    for (; kv0 < kvend; kv0 += 64) {
        bool doA = kv0 < nkA;
        u16x8 pbA[2], pbB[2];

        {
            bf16x8 kf0[4], kf1[4];
#pragma unroll
            for (int sub = 0; sub < 4; ++sub) {
                const u16* kp = kbase + (size_t)((kv0 >> 4) + sub) * 1024;
                kf0[sub] = *reinterpret_cast<const bf16x8*>(kp);
                kf1[sub] = *reinterpret_cast<const bf16x8*>(kp + 512);
            }
            if (doA) {
                f32x4 st[4];
                __builtin_amdgcn_s_setprio(1);
#pragma unroll
                for (int sub = 0; sub < 4; ++sub) {
                    st[sub] = __builtin_amdgcn_mfma_f32_16x16x32_bf16(kf0[sub], qa0, (f32x4){0.f, 0.f, 0.f, 0.f}, 0, 0, 0);
                    st[sub] = __builtin_amdgcn_mfma_f32_16x16x32_bf16(kf1[sub], qa1, st[sub], 0, 0, 0);
                }
                __builtin_amdgcn_s_setprio(0);
                if (kv0 + 64 > qA0) {
#pragma unroll
                    for (int sub = 0; sub < 4; ++sub)
#pragma unroll
                        for (int r = 0; r < 4; ++r) {
                            int key = kv0 + (sub >> 1) * 32 + g * 8 + (sub & 1) * 4 + r;
                            if (key > qrowA) st[sub][r] = -1e30f;
                        }
                }
                float rs = 0.f;
#pragma unroll
                for (int sub = 0; sub < 4; ++sub)
#pragma unroll
                    for (int r = 0; r < 4; ++r) {
                        float e = __builtin_amdgcn_exp2f(st[sub][r]);
                        rs += e;
                        pbA[sub >> 1][(sub & 1) * 4 + r] = f2bf(e);
                    }
                lA += rs;
            }
            f32x4 st[4];
            __builtin_amdgcn_s_setprio(1);
#pragma unroll
            for (int sub = 0; sub < 4; ++sub) {
                st[sub] = __builtin_amdgcn_mfma_f32_16x16x32_bf16(kf0[sub], qb0, (f32x4){0.f, 0.f, 0.f, 0.f}, 0, 0, 0);
                st[sub] = __builtin_amdgcn_mfma_f32_16x16x32_bf16(kf1[sub], qb1, st[sub], 0, 0, 0);
            }
            __builtin_amdgcn_s_setprio(0);
            if (kv0 + 64 > qB0) {
#pragma unroll
                for (int sub = 0; sub < 4; ++sub)
#pragma unroll
                    for (int r = 0; r < 4; ++r) {
                        int key = kv0 + (sub >> 1) * 32 + g * 8 + (sub & 1) * 4 + r;
                        if (key > qrowB) st[sub][r] = -1e30f;
                    }
            }
            float rs = 0.f;
#pragma unroll
            for (int sub = 0; sub < 4; ++sub)
#pragma unroll
                for (int r = 0; r < 4; ++r) {
                    float e = __builtin_amdgcn_exp2f(st[sub][r]);
                    rs += e;
                    pbB[sub >> 1][(sub & 1) * 4 + r] = f2bf(e);
                }
            lB += rs;
        }

        bf16x8 vv[2][4];
#pragma unroll
        for (int sp = 0; sp < 2; ++sp)
#pragma unroll
            for (int dt = 0; dt < 4; ++dt)
                vv[sp][dt] = *reinterpret_cast<const bf16x8*>(
                    vbase + (size_t)((kv0 >> 5) + sp) * 2048 + dt * 512);

        __builtin_amdgcn_s_setprio(1);
#pragma unroll
        for (int sp = 0; sp < 2; ++sp) {
            bf16x8 pa = __builtin_bit_cast(bf16x8, pbA[sp]);
            bf16x8 pb = __builtin_bit_cast(bf16x8, pbB[sp]);
#pragma unroll
            for (int dt = 0; dt < 4; ++dt) {
                if (doA) oA[dt] = __builtin_amdgcn_mfma_f32_16x16x32_bf16(vv[sp][dt], pa, oA[dt], 0, 0, 0);
                oB[dt] = __builtin_amdgcn_mfma_f32_16x16x32_bf16(vv[sp][dt], pb, oB[dt], 0, 0, 0);
            }
        }
        __builtin_amdgcn_s_setprio(0);
    }

    lA += __shfl_xor(lA, 16);
    lA += __shfl_xor(lA, 32);
    lB += __shfl_xor(lB, 16);
    lB += __shfl_xor(lB, 32);
    size_t slotA = ((size_t)h * 160 + item) * 2;
    if (lane < 16) {
        lbuf[slotA * 16 + cc] = lA;
        lbuf[(slotA + 1) * 16 + cc] = lB;
    }
    u16* spA = obuf + slotA * 1024;
    u16* spB = obuf + (slotA + 1) * 1024;
#pragma unroll
    for (int dt = 0; dt < 4; ++dt) {
        u16x4 ovA, ovB;
#pragma unroll
        for (int r = 0; r < 4; ++r) {
            ovA[r] = f2bf(oA[dt][r]);
            ovB[r] = f2bf(oB[dt][r]);
        }
        *reinterpret_cast<u16x4*>(&spA[cc * 64 + dt * 16 + g * 4]) = ovA;
        *reinterpret_cast<u16x4*>(&spB[cc * 64 + dt * 16 + g * 4]) = ovB;
    }
}

// ---------------- merge: attn_bf16 = sum(o_w) / (sum(l_w) + 2^(sink*log2e)) ----------------
__global__ __launch_bounds__(256) void merge_k(const u16* __restrict__ obuf,
                                               const float* __restrict__ lbuf,
                                               const float* __restrict__ sink,
                                               u16* __restrict__ attnb) {
    int row = blockIdx.x;
    int c = row >> 4, cc = row & 15;
    int t2 = c >> 1, half = c & 1;
    int nw = (t2 >> 4) + 1;
    int jb = (t2 < 16) ? t2
           : (t2 < 32) ? 16 + ((t2 - 16) << 1)
           : (t2 < 48) ? 48 + 3 * (t2 - 32)
                       : 96 + ((t2 - 48) << 2);
    int t = threadIdx.x;
    int h = t >> 3, col0 = (t & 7) * 8;

    float acc[8] = {};
    float lsum = __builtin_amdgcn_exp2f(sink[h] * LOG2E);
#pragma unroll 1
    for (int w = 0; w < nw; ++w) {
        size_t slot = ((size_t)h * 160 + jb + w) * 2 + half;
        lsum += lbuf[slot * 16 + cc];
        u16x8 v = *reinterpret_cast<const u16x8*>(&obuf[slot * 1024 + cc * 64 + col0]);
#pragma unroll
        for (int i = 0; i < 8; ++i) acc[i] += bf2f(v[i]);
    }
    float inv = 1.f / lsum;
    u16x8 ob;
#pragma unroll
    for (int i = 0; i < 8; ++i) ob[i] = f2bf(acc[i] * inv);
    *reinterpret_cast<u16x8*>(&attnb[(size_t)row * 2048 + h * 64 + col0]) = ob;
}

extern "C" void kernel_launch(void* const* d_in, const int* in_sizes, int n_in,
                              void* d_out, int out_size, void* d_ws, size_t ws_size,
                              hipStream_t stream) {
    const float* x    = (const float*)d_in[0];
    const float* cosb = (const float*)d_in[2];
    const float* sinb = (const float*)d_in[3];
    const float* wq   = (const float*)d_in[4];
    const float* wk   = (const float*)d_in[5];
    const float* wv   = (const float*)d_in[6];
    const float* wo   = (const float*)d_in[7];
    const float* qw   = (const float*)d_in[8];
    const float* kw   = (const float*)d_in[9];
    const float* sink = (const float*)d_in[10];
    float* out = (float*)d_out;

    char* ws = (char*)d_ws;
    size_t off = 0;
    auto alloc = [&](size_t bytes) {
        char* p = ws + off;
        off += (bytes + 255) & ~(size_t)255;
        return p;
    };
    u16*   xb    = (u16*)alloc((size_t)2048 * 2048 * 2);
    u16*   wqkvt = (u16*)alloc((size_t)3072 * 2048 * 2);
    u16*   wot   = (u16*)alloc((size_t)2048 * 2048 * 2);
    u16*   p0    = (u16*)alloc((size_t)2048 * 3072 * 2);
    u16*   p1    = (u16*)alloc((size_t)2048 * 3072 * 2);
    u16*   qnb   = (u16*)alloc((size_t)2048 * 2048 * 2);
    u16*   kfrag = (u16*)alloc((size_t)8 * 128 * 1024 * 2);
    u16*   vfrag = (u16*)alloc((size_t)8 * 64 * 2048 * 2);
    float* lbuf  = (float*)alloc((size_t)32 * 320 * 16 * 4);
    u16*   attnb = xb;
    u16*   obuf  = p0;
    u16*   o2p   = p0;

    prep_k<<<4608, 256, 0, stream>>>(x, wq, wk, wv, wo, xb, wqkvt, wot);

    gemm_bt_dbuf_k<<<dim3(24, 16, 2), 512, 0, stream>>>(xb, wqkvt, p0, 2048, 3072, 2048);
    postgemm_k<<<20736, 256, 0, stream>>>(p0, p1, cosb, sinb, qw, kw, qnb, kfrag, vfrag);

    attn_k<<<dim3(32, 160), 64, 0, stream>>>(qnb, kfrag, vfrag, obuf, lbuf);
    merge_k<<<2048, 256, 0, stream>>>(obuf, lbuf, sink, attnb);

    gemm_bt_dbuf_k<<<dim3(16, 16, 2), 512, 0, stream>>>(attnb, wot, o2p, 2048, 2048, 2048);
    sum2_f32_k<<<2048, 256, 0, stream>>>(o2p, o2p + (size_t)2048 * 2048, out, 2048 * 2048 / 8);
}